// Round 1
// baseline (6958.527 us; speedup 1.0000x reference)
//
#include <hip/hip_runtime.h>
#include <math.h>

// Problem constants
#define BB 16
#define TT 12
#define NN 1024
#define FF 128
#define HH 8
#define DHH 16
#define CC 64
#define BT (BB*TT)            // 192
#define BTN (BB*TT*NN)        // 196608
#define CNT ((float)BTN)

// Workspace layout (float offsets)
#define OFF_AFF   0
#define OFF_AN2C  524288
#define OFF_AC2N  1048576
#define OFF_V     1572864
#define OFF_T1    26738688            // 1572864 + 25165824
#define OFF_BNSUM 28311552            // OFF_T1 + 192*8192
#define OFF_BNSQ  (OFF_BNSUM+128)
#define OFF_SCALE (OFF_BNSUM+256)
#define OFF_SHIFT (OFF_BNSUM+384)

__device__ __forceinline__ float gelu_f(float x) {
    return 0.5f * x * (1.0f + erff(x * 0.70710678118654752f));
}

// ---------- aff[h,c,n] = (cores[h,c,:] . adaptive[h,:,n]) / sqrt(16) ----------
__global__ __launch_bounds__(256) void k_aff(const float* __restrict__ cores,
                                             const float* __restrict__ adaptive,
                                             float* __restrict__ aff) {
    int idx = blockIdx.x * 256 + threadIdx.x;     // < 524288
    int n  = idx & 1023;
    int hc = idx >> 10;        // h*64+c
    int h  = hc >> 6;
    const float* cp = cores + hc * 16;
    const float* ap = adaptive + h * 16384 + n;
    float s = 0.f;
#pragma unroll
    for (int d = 0; d < 16; ++d) s = fmaf(cp[d], ap[d * 1024], s);
    aff[idx] = s * 0.25f;
}

// ---------- softmax over n (rows of 1024) ----------
__global__ __launch_bounds__(256) void k_sm_n(const float* __restrict__ aff,
                                              float* __restrict__ out) {
    int row = blockIdx.x;                 // h*64+c
    const float* p = aff + row * 1024;
    int t = threadIdx.x;
    __shared__ float red[8];
    float v0 = p[t], v1 = p[t + 256], v2 = p[t + 512], v3 = p[t + 768];
    float m = fmaxf(fmaxf(v0, v1), fmaxf(v2, v3));
#pragma unroll
    for (int off = 32; off >= 1; off >>= 1) m = fmaxf(m, __shfl_xor(m, off));
    if ((t & 63) == 0) red[t >> 6] = m;
    __syncthreads();
    m = fmaxf(fmaxf(red[0], red[1]), fmaxf(red[2], red[3]));
    v0 = expf(v0 - m); v1 = expf(v1 - m); v2 = expf(v2 - m); v3 = expf(v3 - m);
    float s = v0 + v1 + v2 + v3;
#pragma unroll
    for (int off = 32; off >= 1; off >>= 1) s += __shfl_xor(s, off);
    __syncthreads();
    if ((t & 63) == 0) red[4 + (t >> 6)] = s;
    __syncthreads();
    s = red[4] + red[5] + red[6] + red[7];
    float inv = 1.0f / s;
    out[row * 1024 + t]       = v0 * inv;
    out[row * 1024 + t + 256] = v1 * inv;
    out[row * 1024 + t + 512] = v2 * inv;
    out[row * 1024 + t + 768] = v3 * inv;
}

// ---------- softmax over c (per (h,n), stride N) ----------
__global__ __launch_bounds__(256) void k_sm_c(const float* __restrict__ aff,
                                              float* __restrict__ out) {
    int idx = blockIdx.x * 256 + threadIdx.x;   // < 8192
    int n = idx & 1023, h = idx >> 10;
    const float* p = aff + h * 65536 + n;
    float m = -1e30f;
    for (int c = 0; c < 64; ++c) m = fmaxf(m, p[c * 1024]);
    float s = 0.f;
    for (int c = 0; c < 64; ++c) s += expf(p[c * 1024] - m);
    float inv = 1.0f / s;
    for (int c = 0; c < 64; ++c)
        out[h * 65536 + c * 1024 + n] = expf(p[c * 1024] - m) * inv;
}

// ---------- v = input @ Wv + bv   (tile 64 rows x 128 cols) ----------
__global__ __launch_bounds__(256) void k_vproj(const float* __restrict__ input,
                                               const float* __restrict__ Wv,
                                               const float* __restrict__ bv,
                                               float* __restrict__ v) {
    __shared__ float inp_s[64][132];
    int base = blockIdx.x * 64;
    int t = threadIdx.x;
    for (int i = t; i < 2048; i += 256) {        // 64*32 float4
        int r = i >> 5, seg = i & 31;
        *(float4*)&inp_s[r][seg * 4] =
            *(const float4*)&input[(base + r) * 128 + seg * 4];
    }
    __syncthreads();
    int rg = t >> 4;     // 4 rows each
    int cg = t & 15;     // 8 cols each
    float acc[4][8];
#pragma unroll
    for (int j = 0; j < 8; ++j) {
        float bb = bv[cg * 8 + j];
#pragma unroll
        for (int i = 0; i < 4; ++i) acc[i][j] = bb;
    }
    const float* Wp = Wv + cg * 8;
#pragma unroll 4
    for (int k = 0; k < 128; ++k) {
        float wv[8];
        *(float4*)&wv[0] = *(const float4*)(Wp + k * 128);
        *(float4*)&wv[4] = *(const float4*)(Wp + k * 128 + 4);
#pragma unroll
        for (int i = 0; i < 4; ++i) {
            float x = inp_s[rg * 4 + i][k];
#pragma unroll
            for (int j = 0; j < 8; ++j) acc[i][j] = fmaf(x, wv[j], acc[i][j]);
        }
    }
#pragma unroll
    for (int i = 0; i < 4; ++i) {
        float* op = &v[(base + rg * 4 + i) * 128 + cg * 8];
        *(float4*)op       = *(float4*)&acc[i][0];
        *(float4*)(op + 4) = *(float4*)&acc[i][4];
    }
}

// ---------- T1[bt,h,c,dh] = sum_n a_n2c[h,c,n] * v[bt,n,h*16+dh] ----------
__global__ __launch_bounds__(256) void k_stage1(const float* __restrict__ v,
                                                const float* __restrict__ a_n2c,
                                                float* __restrict__ T1) {
    int bt = blockIdx.x, h = blockIdx.y;
    __shared__ float vs[64][16];
    __shared__ float as_s[64][68];
    int t = threadIdx.x;
    int c = t >> 2, dq = t & 3;
    float4 acc = make_float4(0.f, 0.f, 0.f, 0.f);
    for (int n0 = 0; n0 < 1024; n0 += 64) {
        __syncthreads();
        {   // v chunk: 64 rows x 16 cols
            int r = t >> 2, seg = t & 3;
            *(float4*)&vs[r][seg * 4] =
                *(const float4*)&v[(bt * 1024 + n0 + r) * 128 + h * 16 + seg * 4];
        }
        for (int i = t; i < 1024; i += 256) {    // a chunk [64][64] as float4
            int cc = i >> 4, seg = i & 15;
            *(float4*)&as_s[cc][seg * 4] =
                *(const float4*)&a_n2c[(h * 64 + cc) * 1024 + n0 + seg * 4];
        }
        __syncthreads();
#pragma unroll 8
        for (int nn = 0; nn < 64; ++nn) {
            float a = as_s[c][nn];
            float4 vv = *(const float4*)&vs[nn][dq * 4];
            acc.x = fmaf(a, vv.x, acc.x);
            acc.y = fmaf(a, vv.y, acc.y);
            acc.z = fmaf(a, vv.z, acc.z);
            acc.w = fmaf(a, vv.w, acc.w);
        }
    }
    *(float4*)&T1[((bt * 8 + h) * 64 + c) * 16 + dq * 4] = acc;
}

// ---------- fused: stage2(vmix) + concat + FFN + residual + BN partial sums ----------
#define TM 32
__global__ __launch_bounds__(256) void k_ffn(const float* __restrict__ input,
                                             const float* __restrict__ T1,
                                             const float* __restrict__ a_c2n,
                                             const float* __restrict__ W1,
                                             const float* __restrict__ b1,
                                             const float* __restrict__ W2,
                                             const float* __restrict__ b2,
                                             float* __restrict__ out,
                                             float* __restrict__ bn_sum,
                                             float* __restrict__ bn_sq) {
    int bt = blockIdx.y;
    int n0 = blockIdx.x * TM;
    int t = threadIdx.x;
    __shared__ float x2s[TM][260];
    __shared__ float hids[TM][132];
    __shared__ float asl[64][TM + 2];
    __shared__ float red_s[128], red_q[128];
    if (t < 128) { red_s[t] = 0.f; red_q[t] = 0.f; }

    int rowbase = bt * 1024 + n0;
    const float* T1p = T1 + bt * 8192;

    // vmix + build x2 = [input - vmix | vmix]
    for (int h = 0; h < 8; ++h) {
        __syncthreads();
        for (int i = t; i < 64 * TM; i += 256) {
            int cc = i >> 5, r = i & 31;
            asl[cc][r] = a_c2n[(h * 64 + cc) * 1024 + n0 + r];
        }
        __syncthreads();
#pragma unroll
        for (int o = 0; o < 2; ++o) {
            int idx = t + o * 256;
            int r = idx >> 4, dh = idx & 15;
            const float* tp = T1p + h * 1024 + dh;
            float acc = 0.f;
#pragma unroll 8
            for (int cc = 0; cc < 64; ++cc) acc = fmaf(asl[cc][r], tp[cc * 16], acc);
            float inp = input[(rowbase + r) * 128 + h * 16 + dh];
            x2s[r][h * 16 + dh] = inp - acc;
            x2s[r][128 + h * 16 + dh] = acc;
        }
    }
    __syncthreads();

    int rp = t >> 4;   // rows rp and rp+16
    int cb = t & 15;   // cols cb*8 .. +7
    float yacc[2][8];
#pragma unroll
    for (int j = 0; j < 8; ++j) {
        float bb = b2[cb * 8 + j];
        yacc[0][j] = bb; yacc[1][j] = bb;
    }

    for (int ch = 0; ch < 8; ++ch) {
        float hacc[2][8];
#pragma unroll
        for (int j = 0; j < 8; ++j) {
            float bb = b1[ch * 128 + cb * 8 + j];
            hacc[0][j] = bb; hacc[1][j] = bb;
        }
        const float* W1p = W1 + ch * 128 + cb * 8;
#pragma unroll 2
        for (int k = 0; k < 256; ++k) {
            float wv[8];
            *(float4*)&wv[0] = *(const float4*)(W1p + k * 1024);
            *(float4*)&wv[4] = *(const float4*)(W1p + k * 1024 + 4);
            float x0 = x2s[rp][k];
            float x1 = x2s[rp + 16][k];
#pragma unroll
            for (int j = 0; j < 8; ++j) {
                hacc[0][j] = fmaf(x0, wv[j], hacc[0][j]);
                hacc[1][j] = fmaf(x1, wv[j], hacc[1][j]);
            }
        }
        __syncthreads();   // previous chunk's GEMM2 reads of hids are done
#pragma unroll
        for (int i = 0; i < 2; ++i) {
            float g[8];
#pragma unroll
            for (int j = 0; j < 8; ++j) g[j] = gelu_f(hacc[i][j]);
            *(float4*)&hids[rp + i * 16][cb * 8]     = *(float4*)&g[0];
            *(float4*)&hids[rp + i * 16][cb * 8 + 4] = *(float4*)&g[4];
        }
        __syncthreads();
        const float* W2p = W2 + cb * 8;
#pragma unroll 2
        for (int kk = 0; kk < 128; ++kk) {
            float wv[8];
            *(float4*)&wv[0] = *(const float4*)(W2p + (ch * 128 + kk) * 128);
            *(float4*)&wv[4] = *(const float4*)(W2p + (ch * 128 + kk) * 128 + 4);
            float h0 = hids[rp][kk];
            float h1 = hids[rp + 16][kk];
#pragma unroll
            for (int j = 0; j < 8; ++j) {
                yacc[0][j] = fmaf(h0, wv[j], yacc[0][j]);
                yacc[1][j] = fmaf(h1, wv[j], yacc[1][j]);
            }
        }
    }

    // residual + store + BN partials
#pragma unroll
    for (int i = 0; i < 2; ++i) {
        int r = rp + i * 16;
        const float* ip = &input[(rowbase + r) * 128 + cb * 8];
        float4 a = *(const float4*)ip;
        float4 b = *(const float4*)(ip + 4);
        yacc[i][0] += a.x; yacc[i][1] += a.y; yacc[i][2] += a.z; yacc[i][3] += a.w;
        yacc[i][4] += b.x; yacc[i][5] += b.y; yacc[i][6] += b.z; yacc[i][7] += b.w;
        float* op = &out[(rowbase + r) * 128 + cb * 8];
        *(float4*)op       = *(float4*)&yacc[i][0];
        *(float4*)(op + 4) = *(float4*)&yacc[i][4];
    }
#pragma unroll
    for (int j = 0; j < 8; ++j) {
        float p = yacc[0][j] + yacc[1][j];
        float q = yacc[0][j] * yacc[0][j] + yacc[1][j] * yacc[1][j];
        atomicAdd(&red_s[cb * 8 + j], p);
        atomicAdd(&red_q[cb * 8 + j], q);
    }
    __syncthreads();
    if (t < 128) {
        atomicAdd(&bn_sum[t], red_s[t]);
        atomicAdd(&bn_sq[t],  red_q[t]);
    }
}

// ---------- BN finalize: scale/shift per channel ----------
__global__ void k_bnfin(const float* __restrict__ bn_sum, const float* __restrict__ bn_sq,
                        const float* __restrict__ gamma, const float* __restrict__ beta,
                        float* __restrict__ scale, float* __restrict__ shift) {
    int f = threadIdx.x;
    float mean = bn_sum[f] * (1.0f / CNT);
    float var  = bn_sq[f]  * (1.0f / CNT) - mean * mean;
    float sc = gamma[f] * rsqrtf(var + 1e-5f);
    scale[f] = sc;
    shift[f] = beta[f] - mean * sc;
}

// ---------- BN apply (in place on out) ----------
__global__ __launch_bounds__(256) void k_bnapply(float* __restrict__ out,
                                                 const float* __restrict__ scale,
                                                 const float* __restrict__ shift) {
    int idx = blockIdx.x * 256 + threadIdx.x;   // float4 index
    int c = (idx * 4) & 127;
    float4 v = *(float4*)&out[idx * 4];
    float4 sc = *(const float4*)&scale[c];
    float4 sh = *(const float4*)&shift[c];
    v.x = fmaf(v.x, sc.x, sh.x);
    v.y = fmaf(v.y, sc.y, sh.y);
    v.z = fmaf(v.z, sc.z, sh.z);
    v.w = fmaf(v.w, sc.w, sh.w);
    *(float4*)&out[idx * 4] = v;
}

extern "C" void kernel_launch(void* const* d_in, const int* in_sizes, int n_in,
                              void* d_out, int out_size, void* d_ws, size_t ws_size,
                              hipStream_t stream) {
    const float* input    = (const float*)d_in[0];
    const float* Wv       = (const float*)d_in[1];
    const float* bv       = (const float*)d_in[2];
    const float* adaptive = (const float*)d_in[3];
    const float* cores    = (const float*)d_in[4];
    const float* W1       = (const float*)d_in[5];
    const float* b1       = (const float*)d_in[6];
    const float* W2       = (const float*)d_in[7];
    const float* b2       = (const float*)d_in[8];
    const float* gamma    = (const float*)d_in[9];
    const float* beta     = (const float*)d_in[10];
    float* out = (float*)d_out;
    float* ws  = (float*)d_ws;

    float* aff    = ws + OFF_AFF;
    float* a_n2c  = ws + OFF_AN2C;
    float* a_c2n  = ws + OFF_AC2N;
    float* v      = ws + OFF_V;
    float* T1     = ws + OFF_T1;
    float* bn_sum = ws + OFF_BNSUM;
    float* bn_sq  = ws + OFF_BNSQ;
    float* scale  = ws + OFF_SCALE;
    float* shift  = ws + OFF_SHIFT;

    hipMemsetAsync(bn_sum, 0, 256 * sizeof(float), stream);

    k_aff   <<<2048, 256, 0, stream>>>(cores, adaptive, aff);
    k_sm_n  <<<512, 256, 0, stream>>>(aff, a_n2c);
    k_sm_c  <<<32, 256, 0, stream>>>(aff, a_c2n);
    k_vproj <<<BTN / 64, 256, 0, stream>>>(input, Wv, bv, v);
    k_stage1<<<dim3(BT, 8), 256, 0, stream>>>(v, a_n2c, T1);
    k_ffn   <<<dim3(NN / TM, BT), 256, 0, stream>>>(input, T1, a_c2n, W1, b1, W2, b2,
                                                    out, bn_sum, bn_sq);
    k_bnfin <<<1, 128, 0, stream>>>(bn_sum, bn_sq, gamma, beta, scale, shift);
    k_bnapply<<<(out_size / 4) / 256, 256, 0, stream>>>(out, scale, shift);
}

// Round 2
// 687.205 us; speedup vs baseline: 10.1258x; 10.1258x over previous
//
#include <hip/hip_runtime.h>
#include <math.h>

// Problem constants
#define BB 16
#define TT 12
#define NN 1024
#define FF 128
#define BT 192
#define BTN 196608
#define CNT ((float)BTN)

typedef unsigned short ushort_t;
typedef __attribute__((ext_vector_type(8))) short bf16x8;
typedef __attribute__((ext_vector_type(4))) float f32x4;

__device__ __forceinline__ ushort_t f2bf(float x) {
    union { float f; unsigned u; } c; c.f = x;
    unsigned r = c.u + 0x7fffu + ((c.u >> 16) & 1u);
    return (ushort_t)(r >> 16);
}
__device__ __forceinline__ float gelu_f(float x) {
    return 0.5f * x * (1.0f + erff(x * 0.70710678118654752f));
}

// ---------- aff[h,c,n] = (cores[h,c,:] . adaptive[h,:,n]) / sqrt(16) ----------
__global__ __launch_bounds__(256) void k_aff(const float* __restrict__ cores,
                                             const float* __restrict__ adaptive,
                                             float* __restrict__ aff) {
    int idx = blockIdx.x * 256 + threadIdx.x;     // < 524288
    int n  = idx & 1023;
    int hc = idx >> 10;        // h*64+c
    int h  = hc >> 6;
    const float* cp = cores + hc * 16;
    const float* ap = adaptive + h * 16384 + n;
    float s = 0.f;
#pragma unroll
    for (int d = 0; d < 16; ++d) s = fmaf(cp[d], ap[d * 1024], s);
    aff[idx] = s * 0.25f;
}

// ---------- softmax over n (rows of 1024), fp32 out (feeds k_stage1) ----------
__global__ __launch_bounds__(256) void k_sm_n(const float* __restrict__ aff,
                                              float* __restrict__ out) {
    int row = blockIdx.x;                 // h*64+c
    const float* p = aff + row * 1024;
    int t = threadIdx.x;
    __shared__ float red[8];
    float v0 = p[t], v1 = p[t + 256], v2 = p[t + 512], v3 = p[t + 768];
    float m = fmaxf(fmaxf(v0, v1), fmaxf(v2, v3));
#pragma unroll
    for (int off = 32; off >= 1; off >>= 1) m = fmaxf(m, __shfl_xor(m, off));
    if ((t & 63) == 0) red[t >> 6] = m;
    __syncthreads();
    m = fmaxf(fmaxf(red[0], red[1]), fmaxf(red[2], red[3]));
    v0 = expf(v0 - m); v1 = expf(v1 - m); v2 = expf(v2 - m); v3 = expf(v3 - m);
    float s = v0 + v1 + v2 + v3;
#pragma unroll
    for (int off = 32; off >= 1; off >>= 1) s += __shfl_xor(s, off);
    __syncthreads();
    if ((t & 63) == 0) red[4 + (t >> 6)] = s;
    __syncthreads();
    s = red[4] + red[5] + red[6] + red[7];
    float inv = 1.0f / s;
    out[row * 1024 + t]       = v0 * inv;
    out[row * 1024 + t + 256] = v1 * inv;
    out[row * 1024 + t + 512] = v2 * inv;
    out[row * 1024 + t + 768] = v3 * inv;
}

// ---------- softmax over c, output TRANSPOSED bf16: a_c2nT[h][n][c] ----------
__global__ __launch_bounds__(256) void k_sm_c(const float* __restrict__ aff,
                                              ushort_t* __restrict__ a_c2nT) {
    int idx = blockIdx.x * 256 + threadIdx.x;   // < 8192
    int n = idx & 1023, h = idx >> 10;
    const float* p = aff + h * 65536 + n;
    float m = -1e30f;
#pragma unroll 8
    for (int c = 0; c < 64; ++c) m = fmaxf(m, p[c * 1024]);
    float s = 0.f;
#pragma unroll 8
    for (int c = 0; c < 64; ++c) s += expf(p[c * 1024] - m);
    float inv = 1.0f / s;
    ushort_t* op = a_c2nT + (size_t)(h * 1024 + n) * 64;
#pragma unroll 8
    for (int c = 0; c < 64; ++c) op[c] = f2bf(expf(p[c * 1024] - m) * inv);
}

// ---------- v = input @ Wv + bv   (fp32, tile 64x128) ----------
__global__ __launch_bounds__(256) void k_vproj(const float* __restrict__ input,
                                               const float* __restrict__ Wv,
                                               const float* __restrict__ bv,
                                               float* __restrict__ v) {
    __shared__ float inp_s[64][132];
    int base = blockIdx.x * 64;
    int t = threadIdx.x;
    for (int i = t; i < 2048; i += 256) {
        int r = i >> 5, seg = i & 31;
        *(float4*)&inp_s[r][seg * 4] =
            *(const float4*)&input[(size_t)(base + r) * 128 + seg * 4];
    }
    __syncthreads();
    int rg = t >> 4;
    int cg = t & 15;
    float acc[4][8];
#pragma unroll
    for (int j = 0; j < 8; ++j) {
        float bb = bv[cg * 8 + j];
#pragma unroll
        for (int i = 0; i < 4; ++i) acc[i][j] = bb;
    }
    const float* Wp = Wv + cg * 8;
#pragma unroll 4
    for (int k = 0; k < 128; ++k) {
        float wv[8];
        *(float4*)&wv[0] = *(const float4*)(Wp + k * 128);
        *(float4*)&wv[4] = *(const float4*)(Wp + k * 128 + 4);
#pragma unroll
        for (int i = 0; i < 4; ++i) {
            float x = inp_s[rg * 4 + i][k];
#pragma unroll
            for (int j = 0; j < 8; ++j) acc[i][j] = fmaf(x, wv[j], acc[i][j]);
        }
    }
#pragma unroll
    for (int i = 0; i < 4; ++i) {
        float* op = &v[(size_t)(base + rg * 4 + i) * 128 + cg * 8];
        *(float4*)op       = *(float4*)&acc[i][0];
        *(float4*)(op + 4) = *(float4*)&acc[i][4];
    }
}

// ---------- T1t[bt][h][dh][c] (bf16) = sum_n a_n2c[h,c,n] * v[bt,n,h*16+dh] ----------
__global__ __launch_bounds__(256) void k_stage1(const float* __restrict__ v,
                                                const float* __restrict__ a_n2c,
                                                ushort_t* __restrict__ T1t) {
    int bt = blockIdx.x, h = blockIdx.y;
    __shared__ float vs[64][16];
    __shared__ float as_s[64][68];
    int t = threadIdx.x;
    int c = t >> 2, dq = t & 3;
    float4 acc = make_float4(0.f, 0.f, 0.f, 0.f);
    for (int n0 = 0; n0 < 1024; n0 += 64) {
        __syncthreads();
        {
            int r = t >> 2, seg = t & 3;
            *(float4*)&vs[r][seg * 4] =
                *(const float4*)&v[(size_t)(bt * 1024 + n0 + r) * 128 + h * 16 + seg * 4];
        }
        for (int i = t; i < 1024; i += 256) {
            int cc = i >> 4, seg = i & 15;
            *(float4*)&as_s[cc][seg * 4] =
                *(const float4*)&a_n2c[(size_t)(h * 64 + cc) * 1024 + n0 + seg * 4];
        }
        __syncthreads();
#pragma unroll 8
        for (int nn = 0; nn < 64; ++nn) {
            float a = as_s[c][nn];
            float4 vv = *(const float4*)&vs[nn][dq * 4];
            acc.x = fmaf(a, vv.x, acc.x);
            acc.y = fmaf(a, vv.y, acc.y);
            acc.z = fmaf(a, vv.z, acc.z);
            acc.w = fmaf(a, vv.w, acc.w);
        }
    }
    ushort_t* tb = T1t + ((size_t)(bt * 8 + h) * 16) * 64 + c;
    tb[(dq * 4 + 0) * 64] = f2bf(acc.x);
    tb[(dq * 4 + 1) * 64] = f2bf(acc.y);
    tb[(dq * 4 + 2) * 64] = f2bf(acc.z);
    tb[(dq * 4 + 3) * 64] = f2bf(acc.w);
}

// ---------- bf16 weight transposes: W1t[n][k]=W1[k][n], W2t[n][k]=W2[k][n] ----------
__global__ __launch_bounds__(256) void k_wconv(const float* __restrict__ W1,
                                               const float* __restrict__ W2,
                                               ushort_t* __restrict__ W1t,
                                               ushort_t* __restrict__ W2t) {
    int idx = blockIdx.x * 256 + threadIdx.x;  // < 262144
    {
        int nn = idx >> 8, k = idx & 255;
        W1t[idx] = f2bf(W1[(size_t)k * 1024 + nn]);
    }
    if (idx < 131072) {
        int nn = idx >> 10, k = idx & 1023;
        W2t[idx] = f2bf(W2[(size_t)k * 128 + nn]);
    }
}

// ---------- fused MFMA: vmix + concat + FFN + residual + BN partials ----------
__global__ __launch_bounds__(256) void k_ffn(
        const float* __restrict__ input,
        const ushort_t* __restrict__ a_c2nT,
        const ushort_t* __restrict__ T1t,
        const ushort_t* __restrict__ W1t,
        const ushort_t* __restrict__ W2t,
        const float* __restrict__ b1,
        const float* __restrict__ b2,
        float* __restrict__ out,
        float* __restrict__ bn_sum,
        float* __restrict__ bn_sq) {
    __shared__ __align__(16) ushort_t x2s[64][264];   // 64 rows x 256 (+16B pad)
    __shared__ __align__(16) ushort_t hids[64][264];  // 64 rows x 256 (+16B pad)
    int bt = blockIdx.y;
    int n0 = blockIdx.x * 64;
    int t = threadIdx.x;
    int w = t >> 6, lane = t & 63, lr = lane & 15, lg = lane >> 4;
    int rowbase = bt * 1024 + n0;

    // ---- phase A: vmix via MFMA (wave handles its 16 rows), build x2 ----
    {
        int R0 = w * 16;
        const ushort_t* ap = a_c2nT + (size_t)(n0 + R0 + lr) * 64 + lg * 8;
        const ushort_t* tp = T1t + ((size_t)bt * 128 + lr) * 64 + lg * 8;
#pragma unroll
        for (int h = 0; h < 8; ++h) {
            f32x4 vacc = {0.f, 0.f, 0.f, 0.f};
#pragma unroll
            for (int kk = 0; kk < 2; ++kk) {
                bf16x8 af = *(const bf16x8*)(ap + (size_t)h * 65536 + kk * 32);
                bf16x8 bf = *(const bf16x8*)(tp + h * 1024 + kk * 32);
                vacc = __builtin_amdgcn_mfma_f32_16x16x32_bf16(af, bf, vacc, 0, 0, 0);
            }
#pragma unroll
            for (int r = 0; r < 4; ++r) {
                int row = R0 + lg * 4 + r;
                float vm = vacc[r];
                float inp = input[(size_t)(rowbase + row) * 128 + h * 16 + lr];
                x2s[row][h * 16 + lr] = f2bf(inp - vm);
                x2s[row][128 + h * 16 + lr] = f2bf(vm);
            }
        }
    }
    __syncthreads();

    // ---- chunked GEMM1(256-wide) + GELU + GEMM2, wave owns column slices ----
    f32x4 yacc[4][2];
#pragma unroll
    for (int mi = 0; mi < 4; ++mi)
#pragma unroll
        for (int jy = 0; jy < 2; ++jy) {
            float bb = b2[w * 32 + jy * 16 + lr];
            yacc[mi][jy] = (f32x4){bb, bb, bb, bb};
        }

    for (int ch = 0; ch < 4; ++ch) {
        f32x4 hacc[4][4];
#pragma unroll
        for (int mi = 0; mi < 4; ++mi)
#pragma unroll
            for (int jn = 0; jn < 4; ++jn) {
                float bb = b1[ch * 256 + w * 64 + jn * 16 + lr];
                hacc[mi][jn] = (f32x4){bb, bb, bb, bb};
            }
        const ushort_t* w1p = W1t + (size_t)(ch * 256 + w * 64 + lr) * 256 + lg * 8;
#pragma unroll
        for (int kk = 0; kk < 8; ++kk) {
            bf16x8 a4[4];
#pragma unroll
            for (int mi = 0; mi < 4; ++mi)
                a4[mi] = *(const bf16x8*)&x2s[mi * 16 + lr][kk * 32 + lg * 8];
#pragma unroll
            for (int jn = 0; jn < 4; ++jn) {
                bf16x8 bfr = *(const bf16x8*)(w1p + (size_t)jn * 4096 + kk * 32);
#pragma unroll
                for (int mi = 0; mi < 4; ++mi)
                    hacc[mi][jn] = __builtin_amdgcn_mfma_f32_16x16x32_bf16(a4[mi], bfr, hacc[mi][jn], 0, 0, 0);
            }
        }
        __syncthreads();   // prev chunk's GEMM2 hids reads complete
#pragma unroll
        for (int mi = 0; mi < 4; ++mi)
#pragma unroll
            for (int jn = 0; jn < 4; ++jn)
#pragma unroll
                for (int r = 0; r < 4; ++r)
                    hids[mi * 16 + lg * 4 + r][w * 64 + jn * 16 + lr] =
                        f2bf(gelu_f(hacc[mi][jn][r]));
        __syncthreads();   // hids visible to all waves
        const ushort_t* w2p = W2t + (size_t)(w * 32 + lr) * 1024 + ch * 256 + lg * 8;
#pragma unroll
        for (int kk = 0; kk < 8; ++kk) {
            bf16x8 a4[4];
#pragma unroll
            for (int mi = 0; mi < 4; ++mi)
                a4[mi] = *(const bf16x8*)&hids[mi * 16 + lr][kk * 32 + lg * 8];
#pragma unroll
            for (int jy = 0; jy < 2; ++jy) {
                bf16x8 bfr = *(const bf16x8*)(w2p + (size_t)jy * 16384 + kk * 32);
#pragma unroll
                for (int mi = 0; mi < 4; ++mi)
                    yacc[mi][jy] = __builtin_amdgcn_mfma_f32_16x16x32_bf16(a4[mi], bfr, yacc[mi][jy], 0, 0, 0);
            }
        }
    }

    // ---- epilogue: residual + store + BN partial sums ----
    float sacc[2] = {0.f, 0.f}, qacc[2] = {0.f, 0.f};
#pragma unroll
    for (int mi = 0; mi < 4; ++mi)
#pragma unroll
        for (int jy = 0; jy < 2; ++jy)
#pragma unroll
            for (int r = 0; r < 4; ++r) {
                int gr = rowbase + mi * 16 + lg * 4 + r;
                int gc = w * 32 + jy * 16 + lr;
                float val = yacc[mi][jy][r] + input[(size_t)gr * 128 + gc];
                out[(size_t)gr * 128 + gc] = val;
                sacc[jy] += val;
                qacc[jy] += val * val;
            }
#pragma unroll
    for (int jy = 0; jy < 2; ++jy) {
        float s = sacc[jy], q = qacc[jy];
        s += __shfl_xor(s, 16); s += __shfl_xor(s, 32);
        q += __shfl_xor(q, 16); q += __shfl_xor(q, 32);
        if (lg == 0) {
            atomicAdd(&bn_sum[w * 32 + jy * 16 + lr], s);
            atomicAdd(&bn_sq[w * 32 + jy * 16 + lr], q);
        }
    }
}

// ---------- BN finalize ----------
__global__ void k_bnfin(const float* __restrict__ bn_sum, const float* __restrict__ bn_sq,
                        const float* __restrict__ gamma, const float* __restrict__ beta,
                        float* __restrict__ scale, float* __restrict__ shift) {
    int f = threadIdx.x;
    float mean = bn_sum[f] * (1.0f / CNT);
    float var  = bn_sq[f]  * (1.0f / CNT) - mean * mean;
    float sc = gamma[f] * rsqrtf(var + 1e-5f);
    scale[f] = sc;
    shift[f] = beta[f] - mean * sc;
}

// ---------- BN apply (in place) ----------
__global__ __launch_bounds__(256) void k_bnapply(float* __restrict__ out,
                                                 const float* __restrict__ scale,
                                                 const float* __restrict__ shift) {
    size_t idx = (size_t)blockIdx.x * 256 + threadIdx.x;   // float4 index
    int c = (int)((idx * 4) & 127);
    float4 v = *(float4*)&out[idx * 4];
    float4 sc = *(const float4*)&scale[c];
    float4 sh = *(const float4*)&shift[c];
    v.x = fmaf(v.x, sc.x, sh.x);
    v.y = fmaf(v.y, sc.y, sh.y);
    v.z = fmaf(v.z, sc.z, sh.z);
    v.w = fmaf(v.w, sc.w, sh.w);
    *(float4*)&out[idx * 4] = v;
}

extern "C" void kernel_launch(void* const* d_in, const int* in_sizes, int n_in,
                              void* d_out, int out_size, void* d_ws, size_t ws_size,
                              hipStream_t stream) {
    const float* input    = (const float*)d_in[0];
    const float* Wv       = (const float*)d_in[1];
    const float* bv       = (const float*)d_in[2];
    const float* adaptive = (const float*)d_in[3];
    const float* cores    = (const float*)d_in[4];
    const float* W1       = (const float*)d_in[5];
    const float* b1       = (const float*)d_in[6];
    const float* W2       = (const float*)d_in[7];
    const float* b2       = (const float*)d_in[8];
    const float* gamma    = (const float*)d_in[9];
    const float* beta     = (const float*)d_in[10];
    float* out = (float*)d_out;
    float* ws  = (float*)d_ws;

    float* aff      = ws;                                  // 524288 f
    float* a_n2c    = ws + 524288;                         // 524288 f
    ushort_t* a_c2nT = (ushort_t*)(ws + 1048576);          // 524288 us
    float* v        = ws + 1572864;                        // 25165824 f
    ushort_t* T1t   = (ushort_t*)(ws + 26738688);          // 1572864 us
    float* bn_sum   = ws + 28311552;
    float* bn_sq    = bn_sum + 128;
    float* scale    = bn_sum + 256;
    float* shift    = bn_sum + 384;
    // W1t/W2t reuse the aff region (dead after the softmax kernels)
    ushort_t* W1t = (ushort_t*)ws;          // 262144 us
    ushort_t* W2t = W1t + 262144;           // 131072 us

    k_aff   <<<2048, 256, 0, stream>>>(cores, adaptive, aff);
    k_sm_n  <<<512, 256, 0, stream>>>(aff, a_n2c);
    k_sm_c  <<<32, 256, 0, stream>>>(aff, a_c2nT);
    k_wconv <<<1024, 256, 0, stream>>>(W1, W2, W1t, W2t);  // overwrites aff region
    k_vproj <<<BTN / 64, 256, 0, stream>>>(input, Wv, bv, v);
    k_stage1<<<dim3(BT, 8), 256, 0, stream>>>(v, a_n2c, T1t);
    hipMemsetAsync(bn_sum, 0, 256 * sizeof(float), stream);
    k_ffn   <<<dim3(16, BT), 256, 0, stream>>>(input, a_c2nT, T1t, W1t, W2t,
                                               b1, b2, out, bn_sum, bn_sq);
    k_bnfin <<<1, 128, 0, stream>>>(bn_sum, bn_sq, gamma, beta, scale, shift);
    k_bnapply<<<(out_size / 4) / 256, 256, 0, stream>>>(out, scale, shift);
}

// Round 3
// 582.417 us; speedup vs baseline: 11.9477x; 1.1799x over previous
//
#include <hip/hip_runtime.h>
#include <math.h>

// Problem constants
#define BB 16
#define TT 12
#define NN 1024
#define FF 128
#define BT 192
#define BTN 196608
#define CNT ((float)BTN)

typedef unsigned short ushort_t;
typedef __attribute__((ext_vector_type(8))) short bf16x8;
typedef __attribute__((ext_vector_type(4))) float f32x4;

__device__ __forceinline__ ushort_t f2bf(float x) {
    union { float f; unsigned u; } c; c.f = x;
    unsigned r = c.u + 0x7fffu + ((c.u >> 16) & 1u);
    return (ushort_t)(r >> 16);
}
__device__ __forceinline__ float bf2f(ushort_t u) {
    union { unsigned u32; float f; } c; c.u32 = ((unsigned)u) << 16; return c.f;
}
// tanh-form GELU: x * sigmoid(2*0.79788456*(x+0.044715x^3)); |err| < ~1e-3
__device__ __forceinline__ float gelu_f(float x) {
    float u = x * x;
    float s = x * fmaf(u, -0.10294428f, -2.30220852f);  // -2*log2(e)*0.7978..*(1+0.044715u)
    float e = __builtin_amdgcn_exp2f(s);                // e^{-2y}
    return x * __builtin_amdgcn_rcpf(1.0f + e);
}

// ---------- aff[h,c,n] = (cores[h,c,:] . adaptive[h,:,n]) / sqrt(16) ----------
__global__ __launch_bounds__(256) void k_aff(const float* __restrict__ cores,
                                             const float* __restrict__ adaptive,
                                             float* __restrict__ aff) {
    int idx = blockIdx.x * 256 + threadIdx.x;     // < 524288
    int n  = idx & 1023;
    int hc = idx >> 10;
    int h  = hc >> 6;
    const float* cp = cores + hc * 16;
    const float* ap = adaptive + h * 16384 + n;
    float s = 0.f;
#pragma unroll
    for (int d = 0; d < 16; ++d) s = fmaf(cp[d], ap[d * 1024], s);
    aff[idx] = s * 0.25f;
}

// ---------- softmax over n (rows of 1024) -> bf16 a_n2c[h,c,n] ----------
__global__ __launch_bounds__(256) void k_sm_n(const float* __restrict__ aff,
                                              ushort_t* __restrict__ out) {
    int row = blockIdx.x;                 // h*64+c
    const float* p = aff + row * 1024;
    int t = threadIdx.x;
    __shared__ float red[8];
    float v0 = p[t], v1 = p[t + 256], v2 = p[t + 512], v3 = p[t + 768];
    float m = fmaxf(fmaxf(v0, v1), fmaxf(v2, v3));
#pragma unroll
    for (int off = 32; off >= 1; off >>= 1) m = fmaxf(m, __shfl_xor(m, off));
    if ((t & 63) == 0) red[t >> 6] = m;
    __syncthreads();
    m = fmaxf(fmaxf(red[0], red[1]), fmaxf(red[2], red[3]));
    v0 = expf(v0 - m); v1 = expf(v1 - m); v2 = expf(v2 - m); v3 = expf(v3 - m);
    float s = v0 + v1 + v2 + v3;
#pragma unroll
    for (int off = 32; off >= 1; off >>= 1) s += __shfl_xor(s, off);
    __syncthreads();
    if ((t & 63) == 0) red[4 + (t >> 6)] = s;
    __syncthreads();
    s = red[4] + red[5] + red[6] + red[7];
    float inv = 1.0f / s;
    out[row * 1024 + t]       = f2bf(v0 * inv);
    out[row * 1024 + t + 256] = f2bf(v1 * inv);
    out[row * 1024 + t + 512] = f2bf(v2 * inv);
    out[row * 1024 + t + 768] = f2bf(v3 * inv);
}

// ---------- softmax over c -> transposed bf16 a_c2nT[h][n][c], coalesced ----------
__global__ __launch_bounds__(256) void k_sm_c(const float* __restrict__ aff,
                                              ushort_t* __restrict__ a_c2nT) {
    __shared__ ushort_t tile[256][72];
    int b = blockIdx.x;                    // 32 blocks
    int h = b >> 2, n0 = (b & 3) * 256;
    int t = threadIdx.x;
    const float* p = aff + h * 65536 + n0 + t;
    float m = -1e30f;
#pragma unroll 8
    for (int c = 0; c < 64; ++c) m = fmaxf(m, p[c * 1024]);
    float s = 0.f;
#pragma unroll 8
    for (int c = 0; c < 64; ++c) s += expf(p[c * 1024] - m);
    float inv = 1.0f / s;
#pragma unroll 8
    for (int c = 0; c < 64; ++c) tile[t][c] = f2bf(expf(p[c * 1024] - m) * inv);
    __syncthreads();
    ushort_t* ob = a_c2nT + ((size_t)h * 1024 + n0) * 64;
    for (int i = t; i < 2048; i += 256) {
        int r = i >> 3, cq = i & 7;
        *(bf16x8*)&ob[r * 64 + cq * 8] = *(bf16x8*)&tile[r][cq * 8];
    }
}

// ---------- tiled transposes -> bf16: W1t[1024][256], W2t[128][1024], WvT[128][128] ----------
__global__ __launch_bounds__(256) void k_wprep(const float* __restrict__ W1,
                                               const float* __restrict__ W2,
                                               const float* __restrict__ Wv,
                                               ushort_t* __restrict__ W1t,
                                               ushort_t* __restrict__ W2t,
                                               ushort_t* __restrict__ WvT) {
    __shared__ float tile[64][65];
    int b = blockIdx.x;
    const float* src; ushort_t* dst; int C, R, r0, c0;
    if (b < 64)      { src = W1; dst = W1t; R = 256;  C = 1024; r0 = (b >> 4) * 64; c0 = (b & 15) * 64; }
    else if (b < 96) { int q = b - 64; src = W2; dst = W2t; R = 1024; C = 128; r0 = (q >> 1) * 64; c0 = (q & 1) * 64; }
    else             { int q = b - 96; src = Wv; dst = WvT; R = 128;  C = 128; r0 = (q >> 1) * 64; c0 = (q & 1) * 64; }
    int t = threadIdx.x;
    for (int i = t; i < 4096; i += 256) {
        int r = i >> 6, c = i & 63;
        tile[r][c] = src[(size_t)(r0 + r) * C + c0 + c];
    }
    __syncthreads();
    for (int i = t; i < 4096; i += 256) {
        int c = i >> 6, r = i & 63;
        dst[(size_t)(c0 + c) * R + r0 + r] = f2bf(tile[r][c]);
    }
}

// ---------- fused v-proj + stage1 (MFMA): T1t[bt][h][dh][c] bf16 ----------
__global__ __launch_bounds__(256) void k_vs1(const float* __restrict__ input,
                                             const ushort_t* __restrict__ WvT,
                                             const float* __restrict__ bv,
                                             const ushort_t* __restrict__ a_n2c,
                                             ushort_t* __restrict__ T1t) {
    __shared__ __align__(16) ushort_t as_lds[128][136];  // input chunk bf16 [n][f]
    __shared__ __align__(16) ushort_t vsT[128][136];     // v chunk bf16 [f][n]
    int bt = blockIdx.x;
    int t = threadIdx.x, w = t >> 6, lane = t & 63, lr = lane & 15, lg = lane >> 4;

    f32x4 t1acc[2][4];   // [h_local][mi]
#pragma unroll
    for (int hl = 0; hl < 2; ++hl)
#pragma unroll
        for (int mi = 0; mi < 4; ++mi) t1acc[hl][mi] = (f32x4){0.f, 0.f, 0.f, 0.f};

    for (int c8 = 0; c8 < 8; ++c8) {
        int n0 = c8 * 128;
        __syncthreads();   // as_lds consumers (v-GEMM) of prev chunk done
        // stage input chunk 128x128 f32 -> bf16 LDS
        for (int j = 0; j < 16; ++j) {
            int i = j * 256 + t;
            int r = i >> 5, cq = i & 31;
            float4 f = *(const float4*)&input[((size_t)(bt * 1024 + n0 + r)) * 128 + cq * 4];
            union { uint2 d; ushort_t u[4]; } o;
            o.u[0] = f2bf(f.x); o.u[1] = f2bf(f.y); o.u[2] = f2bf(f.z); o.u[3] = f2bf(f.w);
            *(uint2*)&as_lds[r][cq * 4] = o.d;
        }
        __syncthreads();
        // v-GEMM: wave owns n-rows [w*32, w*32+32), all 128 fout
        f32x4 vacc[2][8];
#pragma unroll
        for (int mi = 0; mi < 2; ++mi)
#pragma unroll
            for (int jn = 0; jn < 8; ++jn) {
                float bb = bv[jn * 16 + lr];
                vacc[mi][jn] = (f32x4){bb, bb, bb, bb};
            }
#pragma unroll
        for (int ks = 0; ks < 4; ++ks) {
            bf16x8 a[2];
#pragma unroll
            for (int mi = 0; mi < 2; ++mi)
                a[mi] = *(const bf16x8*)&as_lds[w * 32 + mi * 16 + lr][ks * 32 + lg * 8];
#pragma unroll
            for (int jn = 0; jn < 8; ++jn) {
                bf16x8 bfr = *(const bf16x8*)&WvT[(size_t)(jn * 16 + lr) * 128 + ks * 32 + lg * 8];
#pragma unroll
                for (int mi = 0; mi < 2; ++mi)
                    vacc[mi][jn] = __builtin_amdgcn_mfma_f32_16x16x32_bf16(a[mi], bfr, vacc[mi][jn], 0, 0, 0);
            }
        }
        // write v chunk transposed: vsT[f][n]
#pragma unroll
        for (int mi = 0; mi < 2; ++mi)
#pragma unroll
            for (int jn = 0; jn < 8; ++jn) {
                union { uint2 d; ushort_t u[4]; } o;
                o.u[0] = f2bf(vacc[mi][jn][0]); o.u[1] = f2bf(vacc[mi][jn][1]);
                o.u[2] = f2bf(vacc[mi][jn][2]); o.u[3] = f2bf(vacc[mi][jn][3]);
                *(uint2*)&vsT[jn * 16 + lr][w * 32 + mi * 16 + lg * 4] = o.d;
            }
        __syncthreads();
        // T1 accumulate: wave handles heads w*2, w*2+1
#pragma unroll
        for (int hl = 0; hl < 2; ++hl) {
            int h = w * 2 + hl;
#pragma unroll
            for (int ks = 0; ks < 4; ++ks) {
                bf16x8 bfr = *(const bf16x8*)&vsT[h * 16 + lr][ks * 32 + lg * 8];
#pragma unroll
                for (int mi = 0; mi < 4; ++mi) {
                    bf16x8 a = *(const bf16x8*)&a_n2c[((size_t)(h * 64 + mi * 16 + lr)) * 1024 + n0 + ks * 32 + lg * 8];
                    t1acc[hl][mi] = __builtin_amdgcn_mfma_f32_16x16x32_bf16(a, bfr, t1acc[hl][mi], 0, 0, 0);
                }
            }
        }
    }
    // write T1t: dh=lr, c = mi*16+lg*4+r
#pragma unroll
    for (int hl = 0; hl < 2; ++hl) {
        int h = w * 2 + hl;
#pragma unroll
        for (int mi = 0; mi < 4; ++mi) {
            union { uint2 d; ushort_t u[4]; } o;
            o.u[0] = f2bf(t1acc[hl][mi][0]); o.u[1] = f2bf(t1acc[hl][mi][1]);
            o.u[2] = f2bf(t1acc[hl][mi][2]); o.u[3] = f2bf(t1acc[hl][mi][3]);
            *(uint2*)&T1t[(((size_t)bt * 8 + h) * 16 + lr) * 64 + mi * 16 + lg * 4] = o.d;
        }
    }
}

// ---------- fused MFMA: vmix + concat + FFN + residual + BN partials ----------
__global__ __launch_bounds__(256) void k_ffn(
        const float* __restrict__ input,
        const ushort_t* __restrict__ a_c2nT,
        const ushort_t* __restrict__ T1t,
        const ushort_t* __restrict__ W1t,
        const ushort_t* __restrict__ W2t,
        const float* __restrict__ b1,
        const float* __restrict__ b2,
        float* __restrict__ out,
        float* __restrict__ bn_sum,
        float* __restrict__ bn_sq) {
    __shared__ __align__(16) ushort_t x2s[64][264];
    __shared__ __align__(16) ushort_t hids[64][264];
    int bt = blockIdx.y;
    int n0 = blockIdx.x * 64;
    int t = threadIdx.x;
    int w = t >> 6, lane = t & 63, lr = lane & 15, lg = lane >> 4;
    int rowbase = bt * 1024 + n0;

    // ---- phase A: vmix via MFMA; store right half, then vectorized left half ----
    {
        int R0 = w * 16;
        const ushort_t* ap = a_c2nT + (size_t)(n0 + R0 + lr) * 64 + lg * 8;
        const ushort_t* tp = T1t + ((size_t)bt * 128 + lr) * 64 + lg * 8;
        f32x4 vacc[8];
#pragma unroll
        for (int h = 0; h < 8; ++h) {
            vacc[h] = (f32x4){0.f, 0.f, 0.f, 0.f};
#pragma unroll
            for (int kk = 0; kk < 2; ++kk) {
                bf16x8 af = *(const bf16x8*)(ap + (size_t)h * 65536 + kk * 32);
                bf16x8 bfr = *(const bf16x8*)(tp + h * 1024 + kk * 32);
                vacc[h] = __builtin_amdgcn_mfma_f32_16x16x32_bf16(af, bfr, vacc[h], 0, 0, 0);
            }
        }
#pragma unroll
        for (int h = 0; h < 8; ++h)
#pragma unroll
            for (int r = 0; r < 4; ++r)
                x2s[R0 + lg * 4 + r][128 + h * 16 + lr] = f2bf(vacc[h][r]);
    }
    __syncthreads();
    {   // left half = input - vmix, float4 loads
#pragma unroll
        for (int j = 0; j < 8; ++j) {
            int i = j * 256 + t;
            int row = i >> 5, cq = i & 31;
            float4 f = *(const float4*)&input[((size_t)rowbase + row) * 128 + cq * 4];
            union { uint2 d; ushort_t u[4]; } vm;
            vm.d = *(uint2*)&x2s[row][128 + cq * 4];
            union { uint2 d; ushort_t u[4]; } o;
            o.u[0] = f2bf(f.x - bf2f(vm.u[0]));
            o.u[1] = f2bf(f.y - bf2f(vm.u[1]));
            o.u[2] = f2bf(f.z - bf2f(vm.u[2]));
            o.u[3] = f2bf(f.w - bf2f(vm.u[3]));
            *(uint2*)&x2s[row][cq * 4] = o.d;
        }
    }
    __syncthreads();

    // ---- chunked GEMM1(256-wide) + GELU + GEMM2, wave owns column slices ----
    f32x4 yacc[4][2];
#pragma unroll
    for (int mi = 0; mi < 4; ++mi)
#pragma unroll
        for (int jy = 0; jy < 2; ++jy) {
            float bb = b2[w * 32 + jy * 16 + lr];
            yacc[mi][jy] = (f32x4){bb, bb, bb, bb};
        }

    for (int ch = 0; ch < 4; ++ch) {
        f32x4 hacc[4][4];
#pragma unroll
        for (int mi = 0; mi < 4; ++mi)
#pragma unroll
            for (int jn = 0; jn < 4; ++jn) {
                float bb = b1[ch * 256 + w * 64 + jn * 16 + lr];
                hacc[mi][jn] = (f32x4){bb, bb, bb, bb};
            }
        const ushort_t* w1p = W1t + (size_t)(ch * 256 + w * 64 + lr) * 256 + lg * 8;
#pragma unroll
        for (int kk = 0; kk < 8; ++kk) {
            bf16x8 a4[4];
#pragma unroll
            for (int mi = 0; mi < 4; ++mi)
                a4[mi] = *(const bf16x8*)&x2s[mi * 16 + lr][kk * 32 + lg * 8];
#pragma unroll
            for (int jn = 0; jn < 4; ++jn) {
                bf16x8 bfr = *(const bf16x8*)(w1p + (size_t)jn * 4096 + kk * 32);
#pragma unroll
                for (int mi = 0; mi < 4; ++mi)
                    hacc[mi][jn] = __builtin_amdgcn_mfma_f32_16x16x32_bf16(a4[mi], bfr, hacc[mi][jn], 0, 0, 0);
            }
        }
        __syncthreads();
#pragma unroll
        for (int mi = 0; mi < 4; ++mi)
#pragma unroll
            for (int jn = 0; jn < 4; ++jn)
#pragma unroll
                for (int r = 0; r < 4; ++r)
                    hids[mi * 16 + lg * 4 + r][w * 64 + jn * 16 + lr] =
                        f2bf(gelu_f(hacc[mi][jn][r]));
        __syncthreads();
        const ushort_t* w2p = W2t + (size_t)(w * 32 + lr) * 1024 + ch * 256 + lg * 8;
#pragma unroll
        for (int kk = 0; kk < 8; ++kk) {
            bf16x8 a4[4];
#pragma unroll
            for (int mi = 0; mi < 4; ++mi)
                a4[mi] = *(const bf16x8*)&hids[mi * 16 + lr][kk * 32 + lg * 8];
#pragma unroll
            for (int jy = 0; jy < 2; ++jy) {
                bf16x8 bfr = *(const bf16x8*)(w2p + (size_t)jy * 16384 + kk * 32);
#pragma unroll
                for (int mi = 0; mi < 4; ++mi)
                    yacc[mi][jy] = __builtin_amdgcn_mfma_f32_16x16x32_bf16(a4[mi], bfr, yacc[mi][jy], 0, 0, 0);
            }
        }
    }

    // ---- epilogue: residual + store + BN partial sums ----
    float sacc[2] = {0.f, 0.f}, qacc[2] = {0.f, 0.f};
#pragma unroll
    for (int mi = 0; mi < 4; ++mi)
#pragma unroll
        for (int jy = 0; jy < 2; ++jy)
#pragma unroll
            for (int r = 0; r < 4; ++r) {
                int gr = rowbase + mi * 16 + lg * 4 + r;
                int gc = w * 32 + jy * 16 + lr;
                float val = yacc[mi][jy][r] + input[(size_t)gr * 128 + gc];
                out[(size_t)gr * 128 + gc] = val;
                sacc[jy] += val;
                qacc[jy] += val * val;
            }
#pragma unroll
    for (int jy = 0; jy < 2; ++jy) {
        float s = sacc[jy], q = qacc[jy];
        s += __shfl_xor(s, 16); s += __shfl_xor(s, 32);
        q += __shfl_xor(q, 16); q += __shfl_xor(q, 32);
        if (lg == 0) {
            atomicAdd(&bn_sum[w * 32 + jy * 16 + lr], s);
            atomicAdd(&bn_sq[w * 32 + jy * 16 + lr], q);
        }
    }
}

// ---------- BN finalize ----------
__global__ void k_bnfin(const float* __restrict__ bn_sum, const float* __restrict__ bn_sq,
                        const float* __restrict__ gamma, const float* __restrict__ beta,
                        float* __restrict__ scale, float* __restrict__ shift) {
    int f = threadIdx.x;
    float mean = bn_sum[f] * (1.0f / CNT);
    float var  = bn_sq[f]  * (1.0f / CNT) - mean * mean;
    float sc = gamma[f] * rsqrtf(var + 1e-5f);
    scale[f] = sc;
    shift[f] = beta[f] - mean * sc;
}

// ---------- BN apply (in place) ----------
__global__ __launch_bounds__(256) void k_bnapply(float* __restrict__ out,
                                                 const float* __restrict__ scale,
                                                 const float* __restrict__ shift) {
    size_t idx = (size_t)blockIdx.x * 256 + threadIdx.x;   // float4 index
    int c = (int)((idx * 4) & 127);
    float4 v = *(float4*)&out[idx * 4];
    float4 sc = *(const float4*)&scale[c];
    float4 sh = *(const float4*)&shift[c];
    v.x = fmaf(v.x, sc.x, sh.x);
    v.y = fmaf(v.y, sc.y, sh.y);
    v.z = fmaf(v.z, sc.z, sh.z);
    v.w = fmaf(v.w, sc.w, sh.w);
    *(float4*)&out[idx * 4] = v;
}

extern "C" void kernel_launch(void* const* d_in, const int* in_sizes, int n_in,
                              void* d_out, int out_size, void* d_ws, size_t ws_size,
                              hipStream_t stream) {
    const float* input    = (const float*)d_in[0];
    const float* Wv       = (const float*)d_in[1];
    const float* bv       = (const float*)d_in[2];
    const float* adaptive = (const float*)d_in[3];
    const float* cores    = (const float*)d_in[4];
    const float* W1       = (const float*)d_in[5];
    const float* b1       = (const float*)d_in[6];
    const float* W2       = (const float*)d_in[7];
    const float* b2       = (const float*)d_in[8];
    const float* gamma    = (const float*)d_in[9];
    const float* beta     = (const float*)d_in[10];
    float* out = (float*)d_out;
    float* ws  = (float*)d_ws;

    float*    aff    = ws;                           // 524288 f
    ushort_t* a_n2c  = (ushort_t*)(ws + 524288);     // 524288 us
    ushort_t* a_c2nT = (ushort_t*)(ws + 786432);     // 524288 us
    ushort_t* T1t    = (ushort_t*)(ws + 1048576);    // 1572864 us
    ushort_t* W1t    = (ushort_t*)(ws + 1835008);    // 262144 us
    ushort_t* W2t    = (ushort_t*)(ws + 1966080);    // 131072 us
    ushort_t* WvT    = (ushort_t*)(ws + 2031616);    // 16384 us
    float* bn_sum    = ws + 2039808;
    float* bn_sq     = bn_sum + 128;
    float* scale     = bn_sum + 256;
    float* shift     = bn_sum + 384;

    k_aff   <<<2048, 256, 0, stream>>>(cores, adaptive, aff);
    k_sm_n  <<<512, 256, 0, stream>>>(aff, a_n2c);
    k_sm_c  <<<32, 256, 0, stream>>>(aff, a_c2nT);
    k_wprep <<<100, 256, 0, stream>>>(W1, W2, Wv, W1t, W2t, WvT);
    k_vs1   <<<BT, 256, 0, stream>>>(input, WvT, bv, a_n2c, T1t);
    hipMemsetAsync(bn_sum, 0, 256 * sizeof(float), stream);
    k_ffn   <<<dim3(16, BT), 256, 0, stream>>>(input, a_c2nT, T1t, W1t, W2t,
                                               b1, b2, out, bn_sum, bn_sq);
    k_bnfin <<<1, 128, 0, stream>>>(bn_sum, bn_sq, gamma, beta, scale, shift);
    k_bnapply<<<(out_size / 4) / 256, 256, 0, stream>>>(out, scale, shift);
}

// Round 4
// 531.182 us; speedup vs baseline: 13.1001x; 1.0965x over previous
//
#include <hip/hip_runtime.h>
#include <math.h>

// Problem constants
#define BB 16
#define TT 12
#define NN 1024
#define FF 128
#define BT 192
#define BTN 196608
#define CNT ((float)BTN)

typedef unsigned short ushort_t;
typedef __attribute__((ext_vector_type(8))) short bf16x8;
typedef __attribute__((ext_vector_type(4))) float f32x4;

__device__ __forceinline__ ushort_t f2bf(float x) {
    union { float f; unsigned u; } c; c.f = x;
    unsigned r = c.u + 0x7fffu + ((c.u >> 16) & 1u);
    return (ushort_t)(r >> 16);
}
__device__ __forceinline__ float bf2f(ushort_t u) {
    union { unsigned u32; float f; } c; c.u32 = ((unsigned)u) << 16; return c.f;
}
// tanh-form GELU: x * sigmoid(2*0.79788456*(x+0.044715x^3)); |err| < ~1e-3
__device__ __forceinline__ float gelu_f(float x) {
    float u = x * x;
    float s = x * fmaf(u, -0.10294428f, -2.30220852f);
    float e = __builtin_amdgcn_exp2f(s);
    return x * __builtin_amdgcn_rcpf(1.0f + e);
}

// ---------- aff[h,c,n] = (cores[h,c,:] . adaptive[h,:,n]) / sqrt(16) ----------
__global__ __launch_bounds__(256) void k_aff(const float* __restrict__ cores,
                                             const float* __restrict__ adaptive,
                                             float* __restrict__ aff) {
    int idx = blockIdx.x * 256 + threadIdx.x;     // < 524288
    int n  = idx & 1023;
    int hc = idx >> 10;
    int h  = hc >> 6;
    const float* cp = cores + hc * 16;
    const float* ap = adaptive + h * 16384 + n;
    float s = 0.f;
#pragma unroll
    for (int d = 0; d < 16; ++d) s = fmaf(cp[d], ap[d * 1024], s);
    aff[idx] = s * 0.25f;
}

// ---------- softmax over n (rows of 1024) -> bf16 a_n2c[h,c,n] ----------
__global__ __launch_bounds__(256) void k_sm_n(const float* __restrict__ aff,
                                              ushort_t* __restrict__ out) {
    int row = blockIdx.x;                 // h*64+c
    const float* p = aff + row * 1024;
    int t = threadIdx.x;
    __shared__ float red[8];
    float v0 = p[t], v1 = p[t + 256], v2 = p[t + 512], v3 = p[t + 768];
    float m = fmaxf(fmaxf(v0, v1), fmaxf(v2, v3));
#pragma unroll
    for (int off = 32; off >= 1; off >>= 1) m = fmaxf(m, __shfl_xor(m, off));
    if ((t & 63) == 0) red[t >> 6] = m;
    __syncthreads();
    m = fmaxf(fmaxf(red[0], red[1]), fmaxf(red[2], red[3]));
    v0 = expf(v0 - m); v1 = expf(v1 - m); v2 = expf(v2 - m); v3 = expf(v3 - m);
    float s = v0 + v1 + v2 + v3;
#pragma unroll
    for (int off = 32; off >= 1; off >>= 1) s += __shfl_xor(s, off);
    __syncthreads();
    if ((t & 63) == 0) red[4 + (t >> 6)] = s;
    __syncthreads();
    s = red[4] + red[5] + red[6] + red[7];
    float inv = 1.0f / s;
    out[row * 1024 + t]       = f2bf(v0 * inv);
    out[row * 1024 + t + 256] = f2bf(v1 * inv);
    out[row * 1024 + t + 512] = f2bf(v2 * inv);
    out[row * 1024 + t + 768] = f2bf(v3 * inv);
}

// ---------- softmax over c -> transposed bf16 a_c2nT[h][n][c], coalesced ----------
__global__ __launch_bounds__(256) void k_sm_c(const float* __restrict__ aff,
                                              ushort_t* __restrict__ a_c2nT) {
    __shared__ ushort_t tile[256][72];
    int b = blockIdx.x;                    // 32 blocks
    int h = b >> 2, n0 = (b & 3) * 256;
    int t = threadIdx.x;
    const float* p = aff + h * 65536 + n0 + t;
    float m = -1e30f;
#pragma unroll 8
    for (int c = 0; c < 64; ++c) m = fmaxf(m, p[c * 1024]);
    float s = 0.f;
#pragma unroll 8
    for (int c = 0; c < 64; ++c) s += expf(p[c * 1024] - m);
    float inv = 1.0f / s;
#pragma unroll 8
    for (int c = 0; c < 64; ++c) tile[t][c] = f2bf(expf(p[c * 1024] - m) * inv);
    __syncthreads();
    ushort_t* ob = a_c2nT + ((size_t)h * 1024 + n0) * 64;
    for (int i = t; i < 2048; i += 256) {
        int r = i >> 3, cq = i & 7;
        *(bf16x8*)&ob[r * 64 + cq * 8] = *(bf16x8*)&tile[r][cq * 8];
    }
}

// ---------- tiled transposes -> bf16: W1t[1024][256], W2t[128][1024], WvT[128][128] ----------
__global__ __launch_bounds__(256) void k_wprep(const float* __restrict__ W1,
                                               const float* __restrict__ W2,
                                               const float* __restrict__ Wv,
                                               ushort_t* __restrict__ W1t,
                                               ushort_t* __restrict__ W2t,
                                               ushort_t* __restrict__ WvT) {
    __shared__ float tile[64][65];
    int b = blockIdx.x;
    const float* src; ushort_t* dst; int C, R, r0, c0;
    if (b < 64)      { src = W1; dst = W1t; R = 256;  C = 1024; r0 = (b >> 4) * 64; c0 = (b & 15) * 64; }
    else if (b < 96) { int q = b - 64; src = W2; dst = W2t; R = 1024; C = 128; r0 = (q >> 1) * 64; c0 = (q & 1) * 64; }
    else             { int q = b - 96; src = Wv; dst = WvT; R = 128;  C = 128; r0 = (q >> 1) * 64; c0 = (q & 1) * 64; }
    int t = threadIdx.x;
    for (int i = t; i < 4096; i += 256) {
        int r = i >> 6, c = i & 63;
        tile[r][c] = src[(size_t)(r0 + r) * C + c0 + c];
    }
    __syncthreads();
    for (int i = t; i < 4096; i += 256) {
        int c = i >> 6, r = i & 63;
        dst[(size_t)(c0 + c) * R + r0 + r] = f2bf(tile[r][c]);
    }
}

// ---------- fused v-proj + stage1 (MFMA): T1t[bt][h][dh][c] bf16 ----------
__global__ __launch_bounds__(256) void k_vs1(const float* __restrict__ input,
                                             const ushort_t* __restrict__ WvT,
                                             const float* __restrict__ bv,
                                             const ushort_t* __restrict__ a_n2c,
                                             ushort_t* __restrict__ T1t) {
    __shared__ __align__(16) ushort_t as_lds[128][136];  // input chunk bf16 [n][f]
    __shared__ __align__(16) ushort_t vsT[128][136];     // v chunk bf16 [f][n]
    int bt = blockIdx.x;
    int t = threadIdx.x, w = t >> 6, lane = t & 63, lr = lane & 15, lg = lane >> 4;

    f32x4 t1acc[2][4];   // [h_local][mi]
#pragma unroll
    for (int hl = 0; hl < 2; ++hl)
#pragma unroll
        for (int mi = 0; mi < 4; ++mi) t1acc[hl][mi] = (f32x4){0.f, 0.f, 0.f, 0.f};

    for (int c8 = 0; c8 < 8; ++c8) {
        int n0 = c8 * 128;
        __syncthreads();
        for (int j = 0; j < 16; ++j) {
            int i = j * 256 + t;
            int r = i >> 5, cq = i & 31;
            float4 f = *(const float4*)&input[((size_t)(bt * 1024 + n0 + r)) * 128 + cq * 4];
            union { uint2 d; ushort_t u[4]; } o;
            o.u[0] = f2bf(f.x); o.u[1] = f2bf(f.y); o.u[2] = f2bf(f.z); o.u[3] = f2bf(f.w);
            *(uint2*)&as_lds[r][cq * 4] = o.d;
        }
        __syncthreads();
        f32x4 vacc[2][8];
#pragma unroll
        for (int mi = 0; mi < 2; ++mi)
#pragma unroll
            for (int jn = 0; jn < 8; ++jn) {
                float bb = bv[jn * 16 + lr];
                vacc[mi][jn] = (f32x4){bb, bb, bb, bb};
            }
#pragma unroll
        for (int ks = 0; ks < 4; ++ks) {
            bf16x8 a[2];
#pragma unroll
            for (int mi = 0; mi < 2; ++mi)
                a[mi] = *(const bf16x8*)&as_lds[w * 32 + mi * 16 + lr][ks * 32 + lg * 8];
#pragma unroll
            for (int jn = 0; jn < 8; ++jn) {
                bf16x8 bfr = *(const bf16x8*)&WvT[(size_t)(jn * 16 + lr) * 128 + ks * 32 + lg * 8];
#pragma unroll
                for (int mi = 0; mi < 2; ++mi)
                    vacc[mi][jn] = __builtin_amdgcn_mfma_f32_16x16x32_bf16(a[mi], bfr, vacc[mi][jn], 0, 0, 0);
            }
        }
#pragma unroll
        for (int mi = 0; mi < 2; ++mi)
#pragma unroll
            for (int jn = 0; jn < 8; ++jn) {
                union { uint2 d; ushort_t u[4]; } o;
                o.u[0] = f2bf(vacc[mi][jn][0]); o.u[1] = f2bf(vacc[mi][jn][1]);
                o.u[2] = f2bf(vacc[mi][jn][2]); o.u[3] = f2bf(vacc[mi][jn][3]);
                *(uint2*)&vsT[jn * 16 + lr][w * 32 + mi * 16 + lg * 4] = o.d;
            }
        __syncthreads();
#pragma unroll
        for (int hl = 0; hl < 2; ++hl) {
            int h = w * 2 + hl;
#pragma unroll
            for (int ks = 0; ks < 4; ++ks) {
                bf16x8 bfr = *(const bf16x8*)&vsT[h * 16 + lr][ks * 32 + lg * 8];
#pragma unroll
                for (int mi = 0; mi < 4; ++mi) {
                    bf16x8 a = *(const bf16x8*)&a_n2c[((size_t)(h * 64 + mi * 16 + lr)) * 1024 + n0 + ks * 32 + lg * 8];
                    t1acc[hl][mi] = __builtin_amdgcn_mfma_f32_16x16x32_bf16(a, bfr, t1acc[hl][mi], 0, 0, 0);
                }
            }
        }
    }
#pragma unroll
    for (int hl = 0; hl < 2; ++hl) {
        int h = w * 2 + hl;
#pragma unroll
        for (int mi = 0; mi < 4; ++mi) {
            union { uint2 d; ushort_t u[4]; } o;
            o.u[0] = f2bf(t1acc[hl][mi][0]); o.u[1] = f2bf(t1acc[hl][mi][1]);
            o.u[2] = f2bf(t1acc[hl][mi][2]); o.u[3] = f2bf(t1acc[hl][mi][3]);
            *(uint2*)&T1t[(((size_t)bt * 8 + h) * 16 + lr) * 64 + mi * 16 + lg * 4] = o.d;
        }
    }
}

// ---------- fused MFMA: vmix + concat + FFN + residual + BN partials ----------
// 64 rows x 128-wide hidden chunks (8 chunks): LDS 51.2KB -> 3 blocks/CU.
__global__ __launch_bounds__(256) void k_ffn(
        const float* __restrict__ input,
        const ushort_t* __restrict__ a_c2nT,
        const ushort_t* __restrict__ T1t,
        const ushort_t* __restrict__ W1t,
        const ushort_t* __restrict__ W2t,
        const float* __restrict__ b1,
        const float* __restrict__ b2,
        float* __restrict__ out,
        float* __restrict__ bn_sum,
        float* __restrict__ bn_sq) {
    __shared__ __align__(16) ushort_t x2s[64][264];
    __shared__ __align__(16) ushort_t hids[64][136];
    int bt = blockIdx.y;
    int n0 = blockIdx.x * 64;
    int t = threadIdx.x;
    int w = t >> 6, lane = t & 63, lr = lane & 15, lg = lane >> 4;
    int rowbase = bt * 1024 + n0;

    // ---- phase A: vmix via MFMA; store right half, then vectorized left half ----
    {
        int R0 = w * 16;
        const ushort_t* ap = a_c2nT + (size_t)(n0 + R0 + lr) * 64 + lg * 8;
        const ushort_t* tp = T1t + ((size_t)bt * 128 + lr) * 64 + lg * 8;
        f32x4 vacc[8];
#pragma unroll
        for (int h = 0; h < 8; ++h) {
            vacc[h] = (f32x4){0.f, 0.f, 0.f, 0.f};
#pragma unroll
            for (int kk = 0; kk < 2; ++kk) {
                bf16x8 af = *(const bf16x8*)(ap + (size_t)h * 65536 + kk * 32);
                bf16x8 bfr = *(const bf16x8*)(tp + h * 1024 + kk * 32);
                vacc[h] = __builtin_amdgcn_mfma_f32_16x16x32_bf16(af, bfr, vacc[h], 0, 0, 0);
            }
        }
#pragma unroll
        for (int h = 0; h < 8; ++h)
#pragma unroll
            for (int r = 0; r < 4; ++r)
                x2s[R0 + lg * 4 + r][128 + h * 16 + lr] = f2bf(vacc[h][r]);
    }
    __syncthreads();
    {   // left half = input - vmix, float4 loads
#pragma unroll
        for (int j = 0; j < 8; ++j) {
            int i = j * 256 + t;
            int row = i >> 5, cq = i & 31;
            float4 f = *(const float4*)&input[((size_t)rowbase + row) * 128 + cq * 4];
            union { uint2 d; ushort_t u[4]; } vm;
            vm.d = *(uint2*)&x2s[row][128 + cq * 4];
            union { uint2 d; ushort_t u[4]; } o;
            o.u[0] = f2bf(f.x - bf2f(vm.u[0]));
            o.u[1] = f2bf(f.y - bf2f(vm.u[1]));
            o.u[2] = f2bf(f.z - bf2f(vm.u[2]));
            o.u[3] = f2bf(f.w - bf2f(vm.u[3]));
            *(uint2*)&x2s[row][cq * 4] = o.d;
        }
    }
    __syncthreads();

    // ---- 8 chunks of 128 hidden cols: GEMM1 + GELU + GEMM2 ----
    f32x4 yacc[4][2];
#pragma unroll
    for (int mi = 0; mi < 4; ++mi)
#pragma unroll
        for (int jy = 0; jy < 2; ++jy) {
            float bb = b2[w * 32 + jy * 16 + lr];
            yacc[mi][jy] = (f32x4){bb, bb, bb, bb};
        }

    for (int ch = 0; ch < 8; ++ch) {
        // prefetch GEMM2 B-fragments for this chunk (consumed after 2 barriers)
        bf16x8 b2r[4][2];
        {
            const ushort_t* w2p = W2t + (size_t)(w * 32 + lr) * 1024 + ch * 128 + lg * 8;
#pragma unroll
            for (int kk = 0; kk < 4; ++kk)
#pragma unroll
                for (int jy = 0; jy < 2; ++jy)
                    b2r[kk][jy] = *(const bf16x8*)(w2p + (size_t)jy * 16384 + kk * 32);
        }

        f32x4 hacc[4][2];
#pragma unroll
        for (int mi = 0; mi < 4; ++mi)
#pragma unroll
            for (int jn = 0; jn < 2; ++jn) {
                float bb = b1[ch * 128 + w * 32 + jn * 16 + lr];
                hacc[mi][jn] = (f32x4){bb, bb, bb, bb};
            }
        const ushort_t* w1p = W1t + (size_t)(ch * 128 + w * 32 + lr) * 256 + lg * 8;
#pragma unroll
        for (int kk = 0; kk < 8; ++kk) {
            bf16x8 a4[4];
#pragma unroll
            for (int mi = 0; mi < 4; ++mi)
                a4[mi] = *(const bf16x8*)&x2s[mi * 16 + lr][kk * 32 + lg * 8];
#pragma unroll
            for (int jn = 0; jn < 2; ++jn) {
                bf16x8 bfr = *(const bf16x8*)(w1p + (size_t)jn * 4096 + kk * 32);
#pragma unroll
                for (int mi = 0; mi < 4; ++mi)
                    hacc[mi][jn] = __builtin_amdgcn_mfma_f32_16x16x32_bf16(a4[mi], bfr, hacc[mi][jn], 0, 0, 0);
            }
        }
        __syncthreads();   // prev chunk's GEMM2 hids reads complete
#pragma unroll
        for (int mi = 0; mi < 4; ++mi)
#pragma unroll
            for (int jn = 0; jn < 2; ++jn)
#pragma unroll
                for (int r = 0; r < 4; ++r)
                    hids[mi * 16 + lg * 4 + r][w * 32 + jn * 16 + lr] =
                        f2bf(gelu_f(hacc[mi][jn][r]));
        __syncthreads();   // hids visible to all waves
#pragma unroll
        for (int kk = 0; kk < 4; ++kk) {
            bf16x8 a4[4];
#pragma unroll
            for (int mi = 0; mi < 4; ++mi)
                a4[mi] = *(const bf16x8*)&hids[mi * 16 + lr][kk * 32 + lg * 8];
#pragma unroll
            for (int jy = 0; jy < 2; ++jy)
#pragma unroll
                for (int mi = 0; mi < 4; ++mi)
                    yacc[mi][jy] = __builtin_amdgcn_mfma_f32_16x16x32_bf16(a4[mi], b2r[kk][jy], yacc[mi][jy], 0, 0, 0);
        }
    }

    // ---- epilogue: residual + store + BN partial sums ----
    float sacc[2] = {0.f, 0.f}, qacc[2] = {0.f, 0.f};
#pragma unroll
    for (int mi = 0; mi < 4; ++mi)
#pragma unroll
        for (int jy = 0; jy < 2; ++jy)
#pragma unroll
            for (int r = 0; r < 4; ++r) {
                int gr = rowbase + mi * 16 + lg * 4 + r;
                int gc = w * 32 + jy * 16 + lr;
                float val = yacc[mi][jy][r] + input[(size_t)gr * 128 + gc];
                out[(size_t)gr * 128 + gc] = val;
                sacc[jy] += val;
                qacc[jy] += val * val;
            }
#pragma unroll
    for (int jy = 0; jy < 2; ++jy) {
        float s = sacc[jy], q = qacc[jy];
        s += __shfl_xor(s, 16); s += __shfl_xor(s, 32);
        q += __shfl_xor(q, 16); q += __shfl_xor(q, 32);
        if (lg == 0) {
            atomicAdd(&bn_sum[w * 32 + jy * 16 + lr], s);
            atomicAdd(&bn_sq[w * 32 + jy * 16 + lr], q);
        }
    }
}

// ---------- BN finalize ----------
__global__ void k_bnfin(const float* __restrict__ bn_sum, const float* __restrict__ bn_sq,
                        const float* __restrict__ gamma, const float* __restrict__ beta,
                        float* __restrict__ scale, float* __restrict__ shift) {
    int f = threadIdx.x;
    float mean = bn_sum[f] * (1.0f / CNT);
    float var  = bn_sq[f]  * (1.0f / CNT) - mean * mean;
    float sc = gamma[f] * rsqrtf(var + 1e-5f);
    scale[f] = sc;
    shift[f] = beta[f] - mean * sc;
}

// ---------- BN apply (in place) ----------
__global__ __launch_bounds__(256) void k_bnapply(float* __restrict__ out,
                                                 const float* __restrict__ scale,
                                                 const float* __restrict__ shift) {
    size_t idx = (size_t)blockIdx.x * 256 + threadIdx.x;   // float4 index
    int c = (int)((idx * 4) & 127);
    float4 v = *(float4*)&out[idx * 4];
    float4 sc = *(const float4*)&scale[c];
    float4 sh = *(const float4*)&shift[c];
    v.x = fmaf(v.x, sc.x, sh.x);
    v.y = fmaf(v.y, sc.y, sh.y);
    v.z = fmaf(v.z, sc.z, sh.z);
    v.w = fmaf(v.w, sc.w, sh.w);
    *(float4*)&out[idx * 4] = v;
}

extern "C" void kernel_launch(void* const* d_in, const int* in_sizes, int n_in,
                              void* d_out, int out_size, void* d_ws, size_t ws_size,
                              hipStream_t stream) {
    const float* input    = (const float*)d_in[0];
    const float* Wv       = (const float*)d_in[1];
    const float* bv       = (const float*)d_in[2];
    const float* adaptive = (const float*)d_in[3];
    const float* cores    = (const float*)d_in[4];
    const float* W1       = (const float*)d_in[5];
    const float* b1       = (const float*)d_in[6];
    const float* W2       = (const float*)d_in[7];
    const float* b2       = (const float*)d_in[8];
    const float* gamma    = (const float*)d_in[9];
    const float* beta     = (const float*)d_in[10];
    float* out = (float*)d_out;
    float* ws  = (float*)d_ws;

    float*    aff    = ws;                           // 524288 f
    ushort_t* a_n2c  = (ushort_t*)(ws + 524288);     // 524288 us
    ushort_t* a_c2nT = (ushort_t*)(ws + 786432);     // 524288 us
    ushort_t* T1t    = (ushort_t*)(ws + 1048576);    // 1572864 us
    ushort_t* W1t    = (ushort_t*)(ws + 1835008);    // 262144 us
    ushort_t* W2t    = (ushort_t*)(ws + 1966080);    // 131072 us
    ushort_t* WvT    = (ushort_t*)(ws + 2031616);    // 16384 us
    float* bn_sum    = ws + 2039808;
    float* bn_sq     = bn_sum + 128;
    float* scale     = bn_sum + 256;
    float* shift     = bn_sum + 384;

    k_aff   <<<2048, 256, 0, stream>>>(cores, adaptive, aff);
    k_sm_n  <<<512, 256, 0, stream>>>(aff, a_n2c);
    k_sm_c  <<<32, 256, 0, stream>>>(aff, a_c2nT);
    k_wprep <<<100, 256, 0, stream>>>(W1, W2, Wv, W1t, W2t, WvT);
    k_vs1   <<<BT, 256, 0, stream>>>(input, WvT, bv, a_n2c, T1t);
    hipMemsetAsync(bn_sum, 0, 256 * sizeof(float), stream);
    k_ffn   <<<dim3(16, BT), 256, 0, stream>>>(input, a_c2nT, T1t, W1t, W2t,
                                               b1, b2, out, bn_sum, bn_sq);
    k_bnfin <<<1, 128, 0, stream>>>(bn_sum, bn_sq, gamma, beta, scale, shift);
    k_bnapply<<<(out_size / 4) / 256, 256, 0, stream>>>(out, scale, shift);
}

// Round 5
// 501.615 us; speedup vs baseline: 13.8722x; 1.0589x over previous
//
#include <hip/hip_runtime.h>
#include <math.h>

// Problem constants
#define BB 16
#define TT 12
#define NN 1024
#define FF 128
#define BT 192
#define BTN 196608
#define CNT ((float)BTN)

typedef unsigned short ushort_t;
typedef __attribute__((ext_vector_type(8))) short bf16x8;
typedef __attribute__((ext_vector_type(4))) float f32x4;

__device__ __forceinline__ ushort_t f2bf(float x) {
    union { float f; unsigned u; } c; c.f = x;
    unsigned r = c.u + 0x7fffu + ((c.u >> 16) & 1u);
    return (ushort_t)(r >> 16);
}
__device__ __forceinline__ float bf2f(ushort_t u) {
    union { unsigned u32; float f; } c; c.u32 = ((unsigned)u) << 16; return c.f;
}
// tanh-form GELU
__device__ __forceinline__ float gelu_f(float x) {
    float u = x * x;
    float s = x * fmaf(u, -0.10294428f, -2.30220852f);
    float e = __builtin_amdgcn_exp2f(s);
    return x * __builtin_amdgcn_rcpf(1.0f + e);
}

// swizzled LDS address helpers (byte-granular XOR within a row)
// 512-byte rows: XOR bits 6..8 with row&7  -> column-slice b128 reads are 2-way (free)
__device__ __forceinline__ char* swz512(void* base, int row, int byteoff) {
    return (char*)base + row * 512 + (byteoff ^ ((row & 7) << 6));
}
// 256-byte rows: XOR bits 5..7 with row&7  -> column-slice b128 reads are 4-way
__device__ __forceinline__ char* swz256(void* base, int row, int byteoff) {
    return (char*)base + row * 256 + (byteoff ^ ((row & 7) << 5));
}

// ---------- aff[h,c,n] = (cores[h,c,:] . adaptive[h,:,n]) / sqrt(16) ----------
__global__ __launch_bounds__(256) void k_aff(const float* __restrict__ cores,
                                             const float* __restrict__ adaptive,
                                             float* __restrict__ aff) {
    int idx = blockIdx.x * 256 + threadIdx.x;     // < 524288
    int n  = idx & 1023;
    int hc = idx >> 10;
    int h  = hc >> 6;
    const float* cp = cores + hc * 16;
    const float* ap = adaptive + h * 16384 + n;
    float s = 0.f;
#pragma unroll
    for (int d = 0; d < 16; ++d) s = fmaf(cp[d], ap[d * 1024], s);
    aff[idx] = s * 0.25f;
}

// ---------- softmax over n (rows of 1024) -> bf16 a_n2c[h,c,n] ----------
__global__ __launch_bounds__(256) void k_sm_n(const float* __restrict__ aff,
                                              ushort_t* __restrict__ out) {
    int row = blockIdx.x;                 // h*64+c
    const float* p = aff + row * 1024;
    int t = threadIdx.x;
    __shared__ float red[8];
    float v0 = p[t], v1 = p[t + 256], v2 = p[t + 512], v3 = p[t + 768];
    float m = fmaxf(fmaxf(v0, v1), fmaxf(v2, v3));
#pragma unroll
    for (int off = 32; off >= 1; off >>= 1) m = fmaxf(m, __shfl_xor(m, off));
    if ((t & 63) == 0) red[t >> 6] = m;
    __syncthreads();
    m = fmaxf(fmaxf(red[0], red[1]), fmaxf(red[2], red[3]));
    v0 = expf(v0 - m); v1 = expf(v1 - m); v2 = expf(v2 - m); v3 = expf(v3 - m);
    float s = v0 + v1 + v2 + v3;
#pragma unroll
    for (int off = 32; off >= 1; off >>= 1) s += __shfl_xor(s, off);
    __syncthreads();
    if ((t & 63) == 0) red[4 + (t >> 6)] = s;
    __syncthreads();
    s = red[4] + red[5] + red[6] + red[7];
    float inv = 1.0f / s;
    out[row * 1024 + t]       = f2bf(v0 * inv);
    out[row * 1024 + t + 256] = f2bf(v1 * inv);
    out[row * 1024 + t + 512] = f2bf(v2 * inv);
    out[row * 1024 + t + 768] = f2bf(v3 * inv);
}

// ---------- softmax over c -> transposed bf16 a_c2nT[h][n][c], coalesced ----------
__global__ __launch_bounds__(256) void k_sm_c(const float* __restrict__ aff,
                                              ushort_t* __restrict__ a_c2nT) {
    __shared__ ushort_t tile[256][72];
    int b = blockIdx.x;                    // 32 blocks
    int h = b >> 2, n0 = (b & 3) * 256;
    int t = threadIdx.x;
    const float* p = aff + h * 65536 + n0 + t;
    float m = -1e30f;
#pragma unroll 8
    for (int c = 0; c < 64; ++c) m = fmaxf(m, p[c * 1024]);
    float s = 0.f;
#pragma unroll 8
    for (int c = 0; c < 64; ++c) s += expf(p[c * 1024] - m);
    float inv = 1.0f / s;
#pragma unroll 8
    for (int c = 0; c < 64; ++c) tile[t][c] = f2bf(expf(p[c * 1024] - m) * inv);
    __syncthreads();
    ushort_t* ob = a_c2nT + ((size_t)h * 1024 + n0) * 64;
    for (int i = t; i < 2048; i += 256) {
        int r = i >> 3, cq = i & 7;
        *(bf16x8*)&ob[r * 64 + cq * 8] = *(bf16x8*)&tile[r][cq * 8];
    }
}

// ---------- tiled transposes -> bf16: W1t[1024][256], W2t[128][1024], WvT[128][128] ----------
__global__ __launch_bounds__(256) void k_wprep(const float* __restrict__ W1,
                                               const float* __restrict__ W2,
                                               const float* __restrict__ Wv,
                                               ushort_t* __restrict__ W1t,
                                               ushort_t* __restrict__ W2t,
                                               ushort_t* __restrict__ WvT) {
    __shared__ float tile[64][65];
    int b = blockIdx.x;
    const float* src; ushort_t* dst; int C, R, r0, c0;
    if (b < 64)      { src = W1; dst = W1t; R = 256;  C = 1024; r0 = (b >> 4) * 64; c0 = (b & 15) * 64; }
    else if (b < 96) { int q = b - 64; src = W2; dst = W2t; R = 1024; C = 128; r0 = (q >> 1) * 64; c0 = (q & 1) * 64; }
    else             { int q = b - 96; src = Wv; dst = WvT; R = 128;  C = 128; r0 = (q >> 1) * 64; c0 = (q & 1) * 64; }
    int t = threadIdx.x;
    for (int i = t; i < 4096; i += 256) {
        int r = i >> 6, c = i & 63;
        tile[r][c] = src[(size_t)(r0 + r) * C + c0 + c];
    }
    __syncthreads();
    for (int i = t; i < 4096; i += 256) {
        int c = i >> 6, r = i & 63;
        dst[(size_t)(c0 + c) * R + r0 + r] = f2bf(tile[r][c]);
    }
}

// ---------- fused v-proj + stage1 (MFMA): T1t[bt][h][dh][c] bf16 ----------
// as_lds / vsT: flat 128x128 bf16 (256 B rows), XOR-swizzled
__global__ __launch_bounds__(256) void k_vs1(const float* __restrict__ input,
                                             const ushort_t* __restrict__ WvT,
                                             const float* __restrict__ bv,
                                             const ushort_t* __restrict__ a_n2c,
                                             ushort_t* __restrict__ T1t) {
    __shared__ __align__(16) ushort_t as_lds[128 * 128];
    __shared__ __align__(16) ushort_t vsT[128 * 128];
    int bt = blockIdx.x;
    int t = threadIdx.x, w = t >> 6, lane = t & 63, lr = lane & 15, lg = lane >> 4;

    f32x4 t1acc[2][4];   // [h_local][mi]
#pragma unroll
    for (int hl = 0; hl < 2; ++hl)
#pragma unroll
        for (int mi = 0; mi < 4; ++mi) t1acc[hl][mi] = (f32x4){0.f, 0.f, 0.f, 0.f};

    for (int c8 = 0; c8 < 8; ++c8) {
        int n0 = c8 * 128;
        __syncthreads();
        for (int j = 0; j < 16; ++j) {
            int i = j * 256 + t;
            int r = i >> 5, cq = i & 31;
            float4 f = *(const float4*)&input[((size_t)(bt * 1024 + n0 + r)) * 128 + cq * 4];
            union { uint2 d; ushort_t u[4]; } o;
            o.u[0] = f2bf(f.x); o.u[1] = f2bf(f.y); o.u[2] = f2bf(f.z); o.u[3] = f2bf(f.w);
            *(uint2*)swz256(as_lds, r, cq * 8) = o.d;
        }
        __syncthreads();
        f32x4 vacc[2][8];
#pragma unroll
        for (int mi = 0; mi < 2; ++mi)
#pragma unroll
            for (int jn = 0; jn < 8; ++jn) {
                float bb = bv[jn * 16 + lr];
                vacc[mi][jn] = (f32x4){bb, bb, bb, bb};
            }
#pragma unroll
        for (int ks = 0; ks < 4; ++ks) {
            bf16x8 a[2];
#pragma unroll
            for (int mi = 0; mi < 2; ++mi)
                a[mi] = *(const bf16x8*)swz256(as_lds, w * 32 + mi * 16 + lr, ks * 64 + lg * 16);
#pragma unroll
            for (int jn = 0; jn < 8; ++jn) {
                bf16x8 bfr = *(const bf16x8*)&WvT[(size_t)(jn * 16 + lr) * 128 + ks * 32 + lg * 8];
#pragma unroll
                for (int mi = 0; mi < 2; ++mi)
                    vacc[mi][jn] = __builtin_amdgcn_mfma_f32_16x16x32_bf16(a[mi], bfr, vacc[mi][jn], 0, 0, 0);
            }
        }
#pragma unroll
        for (int mi = 0; mi < 2; ++mi)
#pragma unroll
            for (int jn = 0; jn < 8; ++jn) {
                union { uint2 d; ushort_t u[4]; } o;
                o.u[0] = f2bf(vacc[mi][jn][0]); o.u[1] = f2bf(vacc[mi][jn][1]);
                o.u[2] = f2bf(vacc[mi][jn][2]); o.u[3] = f2bf(vacc[mi][jn][3]);
                *(uint2*)swz256(vsT, jn * 16 + lr, w * 64 + mi * 32 + lg * 8) = o.d;
            }
        __syncthreads();
#pragma unroll
        for (int hl = 0; hl < 2; ++hl) {
            int h = w * 2 + hl;
#pragma unroll
            for (int ks = 0; ks < 4; ++ks) {
                bf16x8 bfr = *(const bf16x8*)swz256(vsT, h * 16 + lr, ks * 64 + lg * 16);
#pragma unroll
                for (int mi = 0; mi < 4; ++mi) {
                    bf16x8 a = *(const bf16x8*)&a_n2c[((size_t)(h * 64 + mi * 16 + lr)) * 1024 + n0 + ks * 32 + lg * 8];
                    t1acc[hl][mi] = __builtin_amdgcn_mfma_f32_16x16x32_bf16(a, bfr, t1acc[hl][mi], 0, 0, 0);
                }
            }
        }
    }
#pragma unroll
    for (int hl = 0; hl < 2; ++hl) {
        int h = w * 2 + hl;
#pragma unroll
        for (int mi = 0; mi < 4; ++mi) {
            union { uint2 d; ushort_t u[4]; } o;
            o.u[0] = f2bf(t1acc[hl][mi][0]); o.u[1] = f2bf(t1acc[hl][mi][1]);
            o.u[2] = f2bf(t1acc[hl][mi][2]); o.u[3] = f2bf(t1acc[hl][mi][3]);
            *(uint2*)&T1t[(((size_t)bt * 8 + h) * 16 + lr) * 64 + mi * 16 + lg * 4] = o.d;
        }
    }
}

// ---------- fused MFMA: vmix + concat + FFN + residual + BN partials ----------
// x2s: flat 64x256 bf16 (512 B rows, swizzled, 32 KB); hids: 64x128 bf16 (256 B rows, 16 KB)
__global__ __launch_bounds__(256) void k_ffn(
        const float* __restrict__ input,
        const ushort_t* __restrict__ a_c2nT,
        const ushort_t* __restrict__ T1t,
        const ushort_t* __restrict__ W1t,
        const ushort_t* __restrict__ W2t,
        const float* __restrict__ b1,
        const float* __restrict__ b2,
        float* __restrict__ out,
        float* __restrict__ bn_sum,
        float* __restrict__ bn_sq) {
    __shared__ __align__(16) ushort_t x2s[64 * 256];
    __shared__ __align__(16) ushort_t hids[64 * 128];
    int bt = blockIdx.y;
    int n0 = blockIdx.x * 64;
    int t = threadIdx.x;
    int w = t >> 6, lane = t & 63, lr = lane & 15, lg = lane >> 4;
    int rowbase = bt * 1024 + n0;

    // ---- phase A: vmix via MFMA; store right half, then vectorized left half ----
    {
        int R0 = w * 16;
        const ushort_t* ap = a_c2nT + (size_t)(n0 + R0 + lr) * 64 + lg * 8;
        const ushort_t* tp = T1t + ((size_t)bt * 128 + lr) * 64 + lg * 8;
        f32x4 vacc[8];
#pragma unroll
        for (int h = 0; h < 8; ++h) {
            vacc[h] = (f32x4){0.f, 0.f, 0.f, 0.f};
#pragma unroll
            for (int kk = 0; kk < 2; ++kk) {
                bf16x8 af = *(const bf16x8*)(ap + (size_t)h * 65536 + kk * 32);
                bf16x8 bfr = *(const bf16x8*)(tp + h * 1024 + kk * 32);
                vacc[h] = __builtin_amdgcn_mfma_f32_16x16x32_bf16(af, bfr, vacc[h], 0, 0, 0);
            }
        }
#pragma unroll
        for (int h = 0; h < 8; ++h)
#pragma unroll
            for (int r = 0; r < 4; ++r) {
                int row = R0 + lg * 4 + r;
                *(ushort_t*)swz512(x2s, row, 256 + (h * 16 + lr) * 2) = f2bf(vacc[h][r]);
            }
    }
    __syncthreads();
    {   // left half = input - vmix, float4 loads
#pragma unroll
        for (int j = 0; j < 8; ++j) {
            int i = j * 256 + t;
            int row = i >> 5, cq = i & 31;
            float4 f = *(const float4*)&input[((size_t)rowbase + row) * 128 + cq * 4];
            union { uint2 d; ushort_t u[4]; } vm;
            vm.d = *(uint2*)swz512(x2s, row, 256 + cq * 8);
            union { uint2 d; ushort_t u[4]; } o;
            o.u[0] = f2bf(f.x - bf2f(vm.u[0]));
            o.u[1] = f2bf(f.y - bf2f(vm.u[1]));
            o.u[2] = f2bf(f.z - bf2f(vm.u[2]));
            o.u[3] = f2bf(f.w - bf2f(vm.u[3]));
            *(uint2*)swz512(x2s, row, cq * 8) = o.d;
        }
    }
    __syncthreads();

    // ---- 8 chunks of 128 hidden cols: GEMM1 + GELU + GEMM2 ----
    f32x4 yacc[4][2];
#pragma unroll
    for (int mi = 0; mi < 4; ++mi)
#pragma unroll
        for (int jy = 0; jy < 2; ++jy) {
            float bb = b2[w * 32 + jy * 16 + lr];
            yacc[mi][jy] = (f32x4){bb, bb, bb, bb};
        }

    for (int ch = 0; ch < 8; ++ch) {
        // prefetch GEMM2 B-fragments for this chunk (consumed after 2 barriers)
        bf16x8 b2r[4][2];
        {
            const ushort_t* w2p = W2t + (size_t)(w * 32 + lr) * 1024 + ch * 128 + lg * 8;
#pragma unroll
            for (int kk = 0; kk < 4; ++kk)
#pragma unroll
                for (int jy = 0; jy < 2; ++jy)
                    b2r[kk][jy] = *(const bf16x8*)(w2p + (size_t)jy * 16384 + kk * 32);
        }

        f32x4 hacc[4][2];
#pragma unroll
        for (int mi = 0; mi < 4; ++mi)
#pragma unroll
            for (int jn = 0; jn < 2; ++jn) {
                float bb = b1[ch * 128 + w * 32 + jn * 16 + lr];
                hacc[mi][jn] = (f32x4){bb, bb, bb, bb};
            }
        const ushort_t* w1p = W1t + (size_t)(ch * 128 + w * 32 + lr) * 256 + lg * 8;
#pragma unroll
        for (int kk = 0; kk < 8; ++kk) {
            bf16x8 a4[4];
#pragma unroll
            for (int mi = 0; mi < 4; ++mi)
                a4[mi] = *(const bf16x8*)swz512(x2s, mi * 16 + lr, kk * 64 + lg * 16);
#pragma unroll
            for (int jn = 0; jn < 2; ++jn) {
                bf16x8 bfr = *(const bf16x8*)(w1p + (size_t)jn * 4096 + kk * 32);
#pragma unroll
                for (int mi = 0; mi < 4; ++mi)
                    hacc[mi][jn] = __builtin_amdgcn_mfma_f32_16x16x32_bf16(a4[mi], bfr, hacc[mi][jn], 0, 0, 0);
            }
        }
        __syncthreads();   // prev chunk's GEMM2 hids reads complete
#pragma unroll
        for (int mi = 0; mi < 4; ++mi)
#pragma unroll
            for (int jn = 0; jn < 2; ++jn)
#pragma unroll
                for (int r = 0; r < 4; ++r) {
                    int m = mi * 16 + lg * 4 + r;
                    *(ushort_t*)swz256(hids, m, (w * 32 + jn * 16 + lr) * 2) =
                        f2bf(gelu_f(hacc[mi][jn][r]));
                }
        __syncthreads();   // hids visible to all waves
#pragma unroll
        for (int kk = 0; kk < 4; ++kk) {
            bf16x8 a4[4];
#pragma unroll
            for (int mi = 0; mi < 4; ++mi)
                a4[mi] = *(const bf16x8*)swz256(hids, mi * 16 + lr, kk * 64 + lg * 16);
#pragma unroll
            for (int jy = 0; jy < 2; ++jy)
#pragma unroll
                for (int mi = 0; mi < 4; ++mi)
                    yacc[mi][jy] = __builtin_amdgcn_mfma_f32_16x16x32_bf16(a4[mi], b2r[kk][jy], yacc[mi][jy], 0, 0, 0);
        }
    }

    // ---- epilogue: residual + store + BN partial sums ----
    float sacc[2] = {0.f, 0.f}, qacc[2] = {0.f, 0.f};
#pragma unroll
    for (int mi = 0; mi < 4; ++mi)
#pragma unroll
        for (int jy = 0; jy < 2; ++jy)
#pragma unroll
            for (int r = 0; r < 4; ++r) {
                int gr = rowbase + mi * 16 + lg * 4 + r;
                int gc = w * 32 + jy * 16 + lr;
                float val = yacc[mi][jy][r] + input[(size_t)gr * 128 + gc];
                out[(size_t)gr * 128 + gc] = val;
                sacc[jy] += val;
                qacc[jy] += val * val;
            }
#pragma unroll
    for (int jy = 0; jy < 2; ++jy) {
        float s = sacc[jy], q = qacc[jy];
        s += __shfl_xor(s, 16); s += __shfl_xor(s, 32);
        q += __shfl_xor(q, 16); q += __shfl_xor(q, 32);
        if (lg == 0) {
            atomicAdd(&bn_sum[w * 32 + jy * 16 + lr], s);
            atomicAdd(&bn_sq[w * 32 + jy * 16 + lr], q);
        }
    }
}

// ---------- BN finalize ----------
__global__ void k_bnfin(const float* __restrict__ bn_sum, const float* __restrict__ bn_sq,
                        const float* __restrict__ gamma, const float* __restrict__ beta,
                        float* __restrict__ scale, float* __restrict__ shift) {
    int f = threadIdx.x;
    float mean = bn_sum[f] * (1.0f / CNT);
    float var  = bn_sq[f]  * (1.0f / CNT) - mean * mean;
    float sc = gamma[f] * rsqrtf(var + 1e-5f);
    scale[f] = sc;
    shift[f] = beta[f] - mean * sc;
}

// ---------- BN apply (in place) ----------
__global__ __launch_bounds__(256) void k_bnapply(float* __restrict__ out,
                                                 const float* __restrict__ scale,
                                                 const float* __restrict__ shift) {
    size_t idx = (size_t)blockIdx.x * 256 + threadIdx.x;   // float4 index
    int c = (int)((idx * 4) & 127);
    float4 v = *(float4*)&out[idx * 4];
    float4 sc = *(const float4*)&scale[c];
    float4 sh = *(const float4*)&shift[c];
    v.x = fmaf(v.x, sc.x, sh.x);
    v.y = fmaf(v.y, sc.y, sh.y);
    v.z = fmaf(v.z, sc.z, sh.z);
    v.w = fmaf(v.w, sc.w, sh.w);
    *(float4*)&out[idx * 4] = v;
}

extern "C" void kernel_launch(void* const* d_in, const int* in_sizes, int n_in,
                              void* d_out, int out_size, void* d_ws, size_t ws_size,
                              hipStream_t stream) {
    const float* input    = (const float*)d_in[0];
    const float* Wv       = (const float*)d_in[1];
    const float* bv       = (const float*)d_in[2];
    const float* adaptive = (const float*)d_in[3];
    const float* cores    = (const float*)d_in[4];
    const float* W1       = (const float*)d_in[5];
    const float* b1       = (const float*)d_in[6];
    const float* W2       = (const float*)d_in[7];
    const float* b2       = (const float*)d_in[8];
    const float* gamma    = (const float*)d_in[9];
    const float* beta     = (const float*)d_in[10];
    float* out = (float*)d_out;
    float* ws  = (float*)d_ws;

    float*    aff    = ws;                           // 524288 f
    ushort_t* a_n2c  = (ushort_t*)(ws + 524288);     // 524288 us
    ushort_t* a_c2nT = (ushort_t*)(ws + 786432);     // 524288 us
    ushort_t* T1t    = (ushort_t*)(ws + 1048576);    // 1572864 us
    ushort_t* W1t    = (ushort_t*)(ws + 1835008);    // 262144 us
    ushort_t* W2t    = (ushort_t*)(ws + 1966080);    // 131072 us
    ushort_t* WvT    = (ushort_t*)(ws + 2031616);    // 16384 us
    float* bn_sum    = ws + 2039808;
    float* bn_sq     = bn_sum + 128;
    float* scale     = bn_sum + 256;
    float* shift     = bn_sum + 384;

    k_aff   <<<2048, 256, 0, stream>>>(cores, adaptive, aff);
    k_sm_n  <<<512, 256, 0, stream>>>(aff, a_n2c);
    k_sm_c  <<<32, 256, 0, stream>>>(aff, a_c2nT);
    k_wprep <<<100, 256, 0, stream>>>(W1, W2, Wv, W1t, W2t, WvT);
    k_vs1   <<<BT, 256, 0, stream>>>(input, WvT, bv, a_n2c, T1t);
    hipMemsetAsync(bn_sum, 0, 256 * sizeof(float), stream);
    k_ffn   <<<dim3(16, BT), 256, 0, stream>>>(input, a_c2nT, T1t, W1t, W2t,
                                               b1, b2, out, bn_sum, bn_sq);
    k_bnfin <<<1, 128, 0, stream>>>(bn_sum, bn_sq, gamma, beta, scale, shift);
    k_bnapply<<<(out_size / 4) / 256, 256, 0, stream>>>(out, scale, shift);
}